// Round 4
// baseline (302.390 us; speedup 1.0000x reference)
//
#include <hip/hip_runtime.h>

// Problem constants (fixed by the reference).
constexpr int N = 100000;   // nodes
constexpr int E = 1600000;  // edges
constexpr int D = 128;      // feature dim (both layers)
constexpr int M = 5000;     // mask size

constexpr int MF_BLKS = (N + 255) / 256;           // 391 mfma-gemm blocks (256 rows each)

// Counting-sort CSR build parameters.
// Bucket = dst>>7 (128 nodes) -> 782 buckets / 782 local-sort blocks.
// Partition uses atomic run-reservation: each partition block reserves a contiguous
// run per bucket via atomicAdd on a global cursor (R3: killed the 3.84x write amp).
constexpr int NBITS = 7;
constexpr int BUCKET = 1 << NBITS;                 // 128 nodes per bucket
constexpr int NB  = (N + BUCKET - 1) / BUCKET;     // 782 buckets
constexpr int EB  = 2048;                          // edges per hist/needed-scan block
constexpr int NPB = (E + EB - 1) / EB;             // 782 hist / needed-scan blocks
constexpr int EBP = 8192;                          // edges per partition block
constexpr int NPP = (E + EBP - 1) / EBP;           // 196 partition blocks (1024 thr each)
constexpr int PREP_BLKS = 32;                      // weight-prep blocks (W1 only, 8192 entries)
constexpr int MB_BLKS = (M + 255) / 256;           // 20 maskbit blocks

typedef __attribute__((ext_vector_type(8))) short bf16x8;
typedef __attribute__((ext_vector_type(4))) float f32x4;

// ---------------- bf16 helpers (RNE pack, cheap unpack) ----------------

__device__ __forceinline__ unsigned int pack_bf16x2(float a, float b) {
    unsigned int ua = __float_as_uint(a);
    unsigned int ub = __float_as_uint(b);
    ua = (ua + 0x7FFFu + ((ua >> 16) & 1u)) >> 16;
    ub = (ub + 0x7FFFu + ((ub >> 16) & 1u)) & 0xFFFF0000u;
    return ua | ub;
}
__device__ __forceinline__ unsigned short bf16_rne(float a) {
    unsigned int ua = __float_as_uint(a);
    return (unsigned short)((ua + 0x7FFFu + ((ua >> 16) & 1u)) >> 16);
}
__device__ __forceinline__ float bf16_lo(unsigned int u) { return __uint_as_float(u << 16); }
__device__ __forceinline__ float bf16_hi(unsigned int u) { return __uint_as_float(u & 0xFFFF0000u); }

// ---------------- misc1: bucket hist (LDS + global atomics) + W1 prep + maskbit ----------------

__global__ __launch_bounds__(256) void k_misc1(const int* __restrict__ dst,
                                               int* __restrict__ bucketCnt,
                                               const float* __restrict__ W1,
                                               unsigned int* __restrict__ Wt1,
                                               const int* __restrict__ mask,
                                               unsigned int* __restrict__ maskbit,
                                               unsigned int* __restrict__ needed) {
    __shared__ int h[NB];
    const int t = threadIdx.x;
    if (blockIdx.x < NPB) {
        for (int i = t; i < NB; i += 256) h[i] = 0;
        __syncthreads();
        const int base = blockIdx.x * EB;
#pragma unroll
        for (int i = 0; i < 8; ++i) {
            int e = base + t + i * 256;
            if (e < E) {
                int b = __builtin_nontemporal_load(dst + e) >> NBITS;
                atomicAdd(&h[b], 1);
            }
        }
        __syncthreads();
        for (int i = t; i < NB; i += 256) {
            int c = h[i];
            if (c) atomicAdd(&bucketCnt[i], c);
        }
    } else if (blockIdx.x < NPB + PREP_BLKS) {
        int idx = (blockIdx.x - NPB) * 256 + t;   // 8192 total (W1 only; W2 used in fp32)
        int n = idx >> 6, kk = idx & 63;
        float a = W1[(2 * kk) * D + n];
        float b = W1[(2 * kk + 1) * D + n];
        Wt1[idx] = pack_bf16x2(a, b);
    } else {
        int i = (blockIdx.x - NPB - PREP_BLKS) * 256 + t;
        if (i < M) {
            int n = mask[i];
            atomicOr(&maskbit[n >> 5], 1u << (n & 31));
            atomicOr(&needed[n >> 5], 1u << (n & 31));  // masked nodes need their own row
        }
    }
}

// ---------------- misc2: bucket scan (1 block) + needed-set edge scan (NPB blocks) ----------------

__global__ __launch_bounds__(256) void k_misc2(const int* __restrict__ bucketCnt,
                                               int* __restrict__ bucketBase,
                                               int* __restrict__ gCursor,
                                               const unsigned int* __restrict__ maskbit,
                                               const int* __restrict__ src,
                                               const int* __restrict__ dst,
                                               unsigned int* __restrict__ needed) {
    const int t = threadIdx.x;
    if (blockIdx.x == 0) {
        // exclusive scan of bucketCnt[0..NB) -> bucketBase[0..NB]; copy to gCursor.
        __shared__ int waveS[4];
        const int lane = t & 63, wave = t >> 6;
        const int idx = t * 4;
        int c[4];
        int s = 0;
#pragma unroll
        for (int g = 0; g < 4; ++g) {
            c[g] = (idx + g < NB) ? bucketCnt[idx + g] : 0;
            s += c[g];
        }
        int v = s;
        for (int off = 1; off < 64; off <<= 1) {
            int u = __shfl_up(v, off);
            if (lane >= off) v += u;
        }
        if (lane == 63) waveS[wave] = v;
        __syncthreads();
        int wb = 0;
        for (int w = 0; w < 4; ++w) if (w < wave) wb += waveS[w];
        int run = wb + v - s;   // exclusive prefix
#pragma unroll
        for (int g = 0; g < 4; ++g) {
            int pos = idx + g;
            if (pos < NB) {
                bucketBase[pos] = run;
                gCursor[pos] = run;
            }
            run += c[g];
        }
        if (t == 255) bucketBase[NB] = E;
    } else {
        const int base = (blockIdx.x - 1) * EB;
#pragma unroll
        for (int i = 0; i < 8; ++i) {
            int e = base + t + i * 256;
            if (e < E) {
                int d = __builtin_nontemporal_load(dst + e);
                if ((maskbit[d >> 5] >> (d & 31)) & 1u) {
                    int s = src[e];
                    atomicOr(&needed[s >> 5], 1u << (s & 31));
                }
            }
        }
    }
}

// ---------------- partition: register-stash + atomic run reservation ----------------
// record: bits[6:0]=d&127, bits[26:7]=src, bits[63:32]=ew bits

__global__ __launch_bounds__(1024) void k_part(const int* __restrict__ src,
                                               const int* __restrict__ dst,
                                               const float* __restrict__ ew,
                                               int* __restrict__ gCursor,
                                               unsigned long long* __restrict__ tmp) {
    __shared__ int cnt[NB];
    __shared__ int off[NB];
    __shared__ int rk[NB];
    const int t = threadIdx.x;
    for (int i = t; i < NB; i += 1024) { cnt[i] = 0; rk[i] = 0; }
    __syncthreads();

    const int eb = blockIdx.x * EBP;
    int d_[8], s_[8];
    float w_[8];
#pragma unroll
    for (int i = 0; i < 8; ++i) {
        int e = eb + t + i * 1024;
        if (e < E) {
            d_[i] = __builtin_nontemporal_load(dst + e);
            s_[i] = __builtin_nontemporal_load(src + e);
            w_[i] = __builtin_nontemporal_load(ew + e);
            atomicAdd(&cnt[d_[i] >> NBITS], 1);
        } else {
            d_[i] = -1;
        }
    }
    __syncthreads();

    for (int i = t; i < NB; i += 1024) {
        int c = cnt[i];
        if (c > 0) off[i] = atomicAdd(&gCursor[i], c);
    }
    __syncthreads();

#pragma unroll
    for (int i = 0; i < 8; ++i) {
        if (d_[i] >= 0) {
            int b = d_[i] >> NBITS;
            int r = atomicAdd(&rk[b], 1);
            unsigned long long rec =
                ((unsigned long long)(unsigned int)__float_as_int(w_[i]) << 32) |
                ((unsigned int)s_[i] << NBITS) | (unsigned int)(d_[i] & (BUCKET - 1));
            tmp[(size_t)off[b] + r] = rec;   // cached store: L2 merges the ~84B runs
        }
    }
}

// ---------------- shared-memory union: GEMM W-tile OR local-sort arrays ----------------

union SMem {
    unsigned int Ws[128 * 68];
    struct { int cnt[BUCKET]; float wsum[BUCKET]; int off[BUCKET]; int waveS[2]; } l;
};

// ---------------- MFMA GEMM body: 256 rows/block, 4 waves; wave = 64 rows x 128 cols ----------------
// A-frag: A[m=lane&15][k=quad*8+j]; B-frag: B[k=quad*8+j][n=lane&15];
// D: col=lane&15, row=quad*4+reg  (HW-verified layouts, 16x16x32 bf16).
// W^T staged in LDS with 68-uint row stride (bank-conflict padding).

template <bool BF16IN>
__device__ __forceinline__ void gemm_mfma_body(unsigned int* __restrict__ Ws,
                                               const void* __restrict__ Xin,
                                               const unsigned int* __restrict__ Wt,
                                               unsigned short* __restrict__ out, int blk) {
    const int t = threadIdx.x;
#pragma unroll
    for (int i = 0; i < 8; ++i) {
        int f4 = t + i * 256;        // uint4 index, 2048 total
        int n = f4 >> 4;
        int k4 = f4 & 15;
        uint4 w = ((const uint4*)Wt)[f4];
        *(uint4*)(&Ws[n * 68 + k4 * 4]) = w;
    }
    __syncthreads();

    const int wv = t >> 6, lane = t & 63;
    const int q = lane >> 4, l15 = lane & 15;
    const int rowBase = blk * 256 + wv * 64;

    f32x4 acc[4][8] = {};
#pragma unroll
    for (int kc = 0; kc < 4; ++kc) {
        bf16x8 af[4];
#pragma unroll
        for (int rt = 0; rt < 4; ++rt) {
            int row = rowBase + rt * 16 + l15;
            if (row > N - 1) row = N - 1;   // tail: duplicate last row, stores guarded
            union { uint4 u; bf16x8 v; } cv;
            if (BF16IN) {
                cv.u = *(const uint4*)((const unsigned int*)Xin + (size_t)row * 64 + kc * 16 + q * 4);
            } else {
                const float* xr = (const float*)Xin + (size_t)row * D + kc * 32 + q * 8;
                float4 x0 = *(const float4*)xr;
                float4 x1 = *(const float4*)(xr + 4);
                cv.u.x = pack_bf16x2(x0.x, x0.y);
                cv.u.y = pack_bf16x2(x0.z, x0.w);
                cv.u.z = pack_bf16x2(x1.x, x1.y);
                cv.u.w = pack_bf16x2(x1.z, x1.w);
            }
            af[rt] = cv.v;
        }
#pragma unroll
        for (int ct = 0; ct < 8; ++ct) {
            union { uint4 u; bf16x8 v; } bv;
            bv.u = *(const uint4*)(&Ws[(ct * 16 + l15) * 68 + kc * 16 + q * 4]);
#pragma unroll
            for (int rt = 0; rt < 4; ++rt)
                acc[rt][ct] = __builtin_amdgcn_mfma_f32_16x16x32_bf16(af[rt], bv.v, acc[rt][ct], 0, 0, 0);
        }
    }

#pragma unroll
    for (int rt = 0; rt < 4; ++rt) {
#pragma unroll
        for (int ct = 0; ct < 8; ++ct) {
            int col = ct * 16 + l15;
#pragma unroll
            for (int r = 0; r < 4; ++r) {
                int row = rowBase + rt * 16 + q * 4 + r;
                if (row < N) out[(size_t)row * D + col] = bf16_rne(acc[rt][ct][r]);
            }
        }
    }
}

// ---- per-bucket local sort body; writes rowStart, dis, node-sorted pairs (src, raw ew) ----

__device__ __forceinline__ void local_body(SMem& sm,
                                           const unsigned long long* __restrict__ tmp,
                                           const int* __restrict__ bucketBase,
                                           float* __restrict__ dis,
                                           int* __restrict__ rowStart,
                                           int2* __restrict__ pairs) {
    const int b = blockIdx.x;
    const int t = threadIdx.x;
    const int segBeg = bucketBase[b];
    const int segEnd = bucketBase[b + 1];

    int*   cnt   = sm.l.cnt;
    float* wsum  = sm.l.wsum;
    int*   off   = sm.l.off;
    int*   waveS = sm.l.waveS;
    if (t < BUCKET) { cnt[t] = 0; wsum[t] = 0.f; }
    __syncthreads();

    for (int e = segBeg + t; e < segEnd; e += 256) {
        unsigned long long rec = tmp[e];
        int dl = (int)(rec & (BUCKET - 1));
        float w = __uint_as_float((unsigned int)(rec >> 32));
        atomicAdd(&cnt[dl], 1);
        atomicAdd(&wsum[dl], w);
    }
    __syncthreads();

    const int lane = t & 63, wv = t >> 6;
    const int pv = (t < BUCKET) ? cnt[t] : 0;
    int v = pv;
    for (int o = 1; o < 64; o <<= 1) {
        int u = __shfl_up(v, o);
        if (lane >= o) v += u;
    }
    if (lane == 63 && wv < 2) waveS[wv] = v;
    __syncthreads();
    if (t < BUCKET) {
        const int wb = (wv == 1) ? waveS[0] : 0;
        const int ex = wb + v - pv;
        off[t] = ex;
        const int node = b * BUCKET + t;
        if (node < N) { rowStart[node] = segBeg + ex; dis[node] = rsqrtf(1.0f + wsum[t]); }
        cnt[t] = 0;
    }
    if (b == NB - 1 && t == 0) rowStart[N] = E;
    __syncthreads();

    for (int e = segBeg + t; e < segEnd; e += 256) {
        unsigned long long rec = tmp[e];
        int dl = (int)(rec & (BUCKET - 1));
        int s  = (int)((rec >> NBITS) & 0xFFFFF);
        unsigned int wbits = (unsigned int)(rec >> 32);
        int r = atomicAdd(&cnt[dl], 1);
        pairs[segBeg + off[dl] + r] = make_int2(s, (int)wbits);
    }
}

// ---------------- fused: local sort (blocks 0..NB) + GEMM1 A=x@W1 (blocks NB..NB+MF_BLKS) ----

__global__ __launch_bounds__(256) void k_local_g1(const unsigned long long* __restrict__ tmp,
                                                  const int* __restrict__ bucketBase,
                                                  float* __restrict__ dis,
                                                  int* __restrict__ rowStart,
                                                  int2* __restrict__ pairs,
                                                  const float* __restrict__ x,
                                                  const unsigned int* __restrict__ Wt1,
                                                  unsigned short* __restrict__ A) {
    __shared__ SMem sm;
    if (blockIdx.x < NB) {
        local_body(sm, tmp, bucketBase, dis, rowStart, pairs);
    } else {
        gemm_mfma_body<false>(sm.Ws, x, Wt1, A, blockIdx.x - NB);
    }
}

// ---------------- aggregate layer 1 (needed nodes only): B = relu(dis*sum + A/deg + b1) ----------------
// One wave per node; lane owns a col-pair. 16-deep gather group: avg degree ~16, so most
// nodes expose ONE latency window (32 gathers in flight) instead of two 8-deep rounds.

__global__ __launch_bounds__(256) void k_aggregate(const unsigned int* __restrict__ Hb,
                                                   const int2* __restrict__ pairs,
                                                   const int* __restrict__ rowStart,
                                                   const float* __restrict__ dis,
                                                   const unsigned int* __restrict__ needed,
                                                   const float* __restrict__ b,
                                                   unsigned int* __restrict__ outB) {
    int node = blockIdx.x * 4 + (threadIdx.x >> 6);
    if (node >= N) return;
    if (!((needed[node >> 5] >> (node & 31)) & 1u)) return;  // row never consumed downstream
    int lane = threadIdx.x & 63;
    int beg = rowStart[node], end = rowStart[node + 1];

    // issue self-row/bias loads early so they overlap the edge loop
    float dd = dis[node];
    unsigned int hs = Hb[(size_t)node * 64 + lane];
    float2 bb = ((const float2*)b)[lane];

    float ax = 0.f, ay = 0.f;
    int j = beg;
    for (; j + 15 < end; j += 16) {
        int2 p[16];
        float vv[16];
        unsigned int h[16];
#pragma unroll
        for (int i = 0; i < 16; ++i) p[i] = pairs[j + i];
#pragma unroll
        for (int i = 0; i < 16; ++i) { h[i] = Hb[(size_t)p[i].x * 64 + lane]; vv[i] = dis[p[i].x]; }
#pragma unroll
        for (int i = 0; i < 16; ++i) {
            float v = __int_as_float(p[i].y) * vv[i];
            ax += bf16_lo(h[i]) * v;
            ay += bf16_hi(h[i]) * v;
        }
    }
    for (; j + 7 < end; j += 8) {
        int2 p[8];
        float vv[8];
        unsigned int h[8];
#pragma unroll
        for (int i = 0; i < 8; ++i) p[i] = pairs[j + i];
#pragma unroll
        for (int i = 0; i < 8; ++i) { h[i] = Hb[(size_t)p[i].x * 64 + lane]; vv[i] = dis[p[i].x]; }
#pragma unroll
        for (int i = 0; i < 8; ++i) {
            float v = __int_as_float(p[i].y) * vv[i];
            ax += bf16_lo(h[i]) * v;
            ay += bf16_hi(h[i]) * v;
        }
    }
    for (; j + 3 < end; j += 4) {
        int2 p[4];
        float vv[4];
        unsigned int h[4];
#pragma unroll
        for (int i = 0; i < 4; ++i) p[i] = pairs[j + i];
#pragma unroll
        for (int i = 0; i < 4; ++i) { h[i] = Hb[(size_t)p[i].x * 64 + lane]; vv[i] = dis[p[i].x]; }
#pragma unroll
        for (int i = 0; i < 4; ++i) {
            float v = __int_as_float(p[i].y) * vv[i];
            ax += bf16_lo(h[i]) * v;
            ay += bf16_hi(h[i]) * v;
        }
    }
    for (; j < end; ++j) {
        int2 p0 = pairs[j];
        unsigned int h0 = Hb[(size_t)p0.x * 64 + lane];
        float v0 = __int_as_float(p0.y) * dis[p0.x];
        ax += bf16_lo(h0) * v0;
        ay += bf16_hi(h0) * v0;
    }

    float sn = dd * dd;  // self-loop norm = 1/deg
    float ox = fmaxf(ax * dd + bf16_lo(hs) * sn + bb.x, 0.f);
    float oy = fmaxf(ay * dd + bf16_hi(hs) * sn + bb.y, 0.f);
    __builtin_nontemporal_store(pack_bf16x2(ox, oy), outB + (size_t)node * 64 + lane);
}

// ---------------- layer-2: aggregation is LINEAR, so agg(B@W2) = agg(B)@W2. ----------------
// Aggregate B at mask nodes (fp32, no bias) -> aggB [M x 128], then a tiny fp32 GEMM
// aggB@W2 + b2 -> out. Kills the full-N k_gemm2 (25.6MB read + 25.6MB write + MFMA).

__global__ __launch_bounds__(256) void k_agg_mask_B(const unsigned int* __restrict__ Hb,
                                                    const int2* __restrict__ pairs,
                                                    const int* __restrict__ rowStart,
                                                    const float* __restrict__ dis,
                                                    const int* __restrict__ mask,
                                                    const int* __restrict__ y,
                                                    float* __restrict__ aggB,
                                                    float* __restrict__ out) {
    int i = blockIdx.x * 4 + (threadIdx.x >> 6);
    if (i >= M) return;
    int lane = threadIdx.x & 63;
    int node = mask[i];
    int beg = rowStart[node], end = rowStart[node + 1];

    float dd = dis[node];
    unsigned int hs = Hb[(size_t)node * 64 + lane];

    float ax = 0.f, ay = 0.f;
    int j = beg;
    for (; j + 15 < end; j += 16) {
        int2 p[16];
        float vv[16];
        unsigned int h[16];
#pragma unroll
        for (int ii = 0; ii < 16; ++ii) p[ii] = pairs[j + ii];
#pragma unroll
        for (int ii = 0; ii < 16; ++ii) { h[ii] = Hb[(size_t)p[ii].x * 64 + lane]; vv[ii] = dis[p[ii].x]; }
#pragma unroll
        for (int ii = 0; ii < 16; ++ii) {
            float v = __int_as_float(p[ii].y) * vv[ii];
            ax += bf16_lo(h[ii]) * v;
            ay += bf16_hi(h[ii]) * v;
        }
    }
    for (; j + 7 < end; j += 8) {
        int2 p[8];
        float vv[8];
        unsigned int h[8];
#pragma unroll
        for (int ii = 0; ii < 8; ++ii) p[ii] = pairs[j + ii];
#pragma unroll
        for (int ii = 0; ii < 8; ++ii) { h[ii] = Hb[(size_t)p[ii].x * 64 + lane]; vv[ii] = dis[p[ii].x]; }
#pragma unroll
        for (int ii = 0; ii < 8; ++ii) {
            float v = __int_as_float(p[ii].y) * vv[ii];
            ax += bf16_lo(h[ii]) * v;
            ay += bf16_hi(h[ii]) * v;
        }
    }
    for (; j < end; ++j) {
        int2 p0 = pairs[j];
        unsigned int h0 = Hb[(size_t)p0.x * 64 + lane];
        float v0 = __int_as_float(p0.y) * dis[p0.x];
        ax += bf16_lo(h0) * v0;
        ay += bf16_hi(h0) * v0;
    }

    float sn = dd * dd;
    float ox = ax * dd + bf16_lo(hs) * sn;   // NO bias here; b2 added after the GEMM
    float oy = ay * dd + bf16_hi(hs) * sn;
    ((float2*)(aggB + (size_t)i * D))[lane] = make_float2(ox, oy);
    if (lane == 0) out[(size_t)M * D + i] = (float)y[node];
}

// ---- out = aggB @ W2 + b2, all fp32 (more accurate than the old bf16-MFMA path). ----
// 4 rows/block (wave per row); W2 (64KB) + the 4 aggB rows staged in LDS.

__global__ __launch_bounds__(256) void k_out_gemm(const float* __restrict__ aggB,
                                                  const float* __restrict__ W2,
                                                  const float* __restrict__ b2,
                                                  float* __restrict__ out) {
    __shared__ float w2s[128 * 132];   // pad 132: 16B-aligned float4 stores, bank spread
    __shared__ float rowL[4][128];
    const int t = threadIdx.x;
    const int wv = t >> 6, lane = t & 63;
    const int row = blockIdx.x * 4 + wv;   // grid = M/4 exactly (1250*4 = 5000)

    for (int i = t; i < 4096; i += 256) {
        float4 v = ((const float4*)W2)[i];
        int k = (4 * i) >> 7, n = (4 * i) & 127;
        *(float4*)(&w2s[k * 132 + n]) = v;
    }
    float2 a2 = ((const float2*)(aggB + (size_t)row * D))[lane];
    rowL[wv][2 * lane] = a2.x;
    rowL[wv][2 * lane + 1] = a2.y;
    __syncthreads();

    float2 bb = ((const float2*)b2)[lane];
    float acc0 = bb.x, acc1 = bb.y;
#pragma unroll 8
    for (int k = 0; k < 128; ++k) {
        float a = rowL[wv][k];
        float2 w = *(const float2*)(&w2s[k * 132 + 2 * lane]);
        acc0 += a * w.x;
        acc1 += a * w.y;
    }
    ((float2*)(out + (size_t)row * D))[lane] = make_float2(acc0, acc1);
}

extern "C" void kernel_launch(void* const* d_in, const int* in_sizes, int n_in,
                              void* d_out, int out_size, void* d_ws, size_t ws_size,
                              hipStream_t stream) {
    const float* x  = (const float*)d_in[0];
    const float* ew = (const float*)d_in[1];
    const float* W1 = (const float*)d_in[2];
    const float* b1 = (const float*)d_in[3];
    const float* W2 = (const float*)d_in[4];
    const float* b2 = (const float*)d_in[5];
    const int* eidx = (const int*)d_in[6];
    const int* mask = (const int*)d_in[7];
    const int* y    = (const int*)d_in[8];
    const int* src = eidx;       // edge_index[0]
    const int* dst = eidx + E;   // edge_index[1]

    // Workspace layout (bytes):
    //   dis        @ 0       : N f32       (0.4 MB)
    //   rowStart   @ 512 KB  : N+1 i32     (0.4 MB)
    //   maskbit    @ 960 KB  : 16 KB bitmap }
    //   needed     @ 976 KB  : 16 KB bitmap }  zeroed together (40 KB memset)
    //   bucketCnt  @ 992 KB  : NB i32          }
    //   bucketBase @ 996 KB  : NB+1 i32
    //   gCursor    @ 1000 KB : NB i32
    //   Wt1        @ 1008 KB : 8192 u32   (32 KB)
    //   pairs      @ 2 MB    : E int2     (12.8 MB)
    //   tmp        @ 16 MB   : E u64      (12.8 MB)
    //   A  (bf16)  @ 29 MB   : N*D bf16   (25.6 MB)
    //   B  (bf16)  @ 55 MB   : N*D bf16   (25.6 MB)
    //   aggB (f32) @ 81 MB   : M*D f32    (2.56 MB)   total ~84 MB
    char* ws = (char*)d_ws;
    float* dis      = (float*)(ws);
    int*   rowStart = (int*)(ws + (size_t)512 * 1024);
    unsigned int* maskbit = (unsigned int*)(ws + (size_t)960 * 1024);
    unsigned int* needed  = (unsigned int*)(ws + (size_t)976 * 1024);
    int*   bucketCnt  = (int*)(ws + (size_t)992 * 1024);
    int*   bucketBase = (int*)(ws + (size_t)996 * 1024);
    int*   gCursor    = (int*)(ws + (size_t)1000 * 1024);
    unsigned int* Wt1 = (unsigned int*)(ws + (size_t)1008 * 1024);
    int2*  pairs    = (int2*)(ws + (size_t)2 * 1024 * 1024);
    unsigned long long* tmp = (unsigned long long*)(ws + (size_t)16 * 1024 * 1024);
    unsigned short* A  = (unsigned short*)(ws + (size_t)29 * 1024 * 1024);
    unsigned short* B  = (unsigned short*)(ws + (size_t)55 * 1024 * 1024);
    float* aggB = (float*)(ws + (size_t)81 * 1024 * 1024);

    // --- zero bitmaps + bucket counters, then fused hist + W1 prep + maskbit ---
    (void)hipMemsetAsync(ws + (size_t)960 * 1024, 0, (size_t)40 * 1024, stream);
    hipLaunchKernelGGL(k_misc1, dim3(NPB + PREP_BLKS + MB_BLKS), dim3(256), 0, stream,
                       dst, bucketCnt, W1, Wt1, mask, maskbit, needed);

    // --- bucket scan (1 block) + needed-set edge scan ---
    hipLaunchKernelGGL(k_misc2, dim3(1 + NPB), dim3(256), 0, stream,
                       bucketCnt, bucketBase, gCursor, maskbit, src, dst, needed);

    // --- partition via atomic run reservation ---
    hipLaunchKernelGGL(k_part, dim3(NPP), dim3(1024), 0, stream,
                       src, dst, ew, gCursor, tmp);
    hipLaunchKernelGGL(k_local_g1, dim3(NB + MF_BLKS), dim3(256), 0, stream,
                       tmp, bucketBase, dis, rowStart, pairs, x, Wt1, A);

    // --- layer 1 aggregate at needed nodes only: B = relu(agg(A) + b1) ---
    hipLaunchKernelGGL(k_aggregate, dim3((N + 3) / 4), dim3(256), 0, stream,
                       (const unsigned int*)A, pairs, rowStart, dis, needed, b1,
                       (unsigned int*)B);

    // --- layer 2 (linearity): aggB = agg(B) at mask nodes; out = aggB@W2 + b2 ---
    hipLaunchKernelGGL(k_agg_mask_B, dim3((M + 3) / 4), dim3(256), 0, stream,
                       (const unsigned int*)B, pairs, rowStart, dis, mask, y,
                       aggB, (float*)d_out);
    hipLaunchKernelGGL(k_out_gemm, dim3(M / 4), dim3(256), 0, stream,
                       aggB, W2, b2, (float*)d_out);
}

// Round 5
// 287.207 us; speedup vs baseline: 1.0529x; 1.0529x over previous
//
#include <hip/hip_runtime.h>

// Problem constants (fixed by the reference).
constexpr int N = 100000;   // nodes
constexpr int E = 1600000;  // edges
constexpr int D = 128;      // feature dim (both layers)
constexpr int M = 5000;     // mask size

constexpr int MF_BLKS = (N + 255) / 256;           // 391 mfma-gemm blocks (256 rows each)

// Counting-sort CSR build parameters.
// Bucket = dst>>7 (128 nodes) -> 782 buckets / 782 local-sort blocks.
// Partition uses atomic run-reservation (R3: killed the 3.84x write amp).
// Local sort is split: pass-A (counts -> rowStart, dis, cursors), pass-B (scatter
// pairs with ew*dis[src] pre-multiplied) -- removes one vmem instr per edge from
// BOTH aggregate kernels (R4 theory: aggregate is vmem-issue/latency bound).
constexpr int NBITS = 7;
constexpr int BUCKET = 1 << NBITS;                 // 128 nodes per bucket
constexpr int NB  = (N + BUCKET - 1) / BUCKET;     // 782 buckets
constexpr int EB  = 2048;                          // edges per hist/needed-scan block
constexpr int NPB = (E + EB - 1) / EB;             // 782 hist / needed-scan blocks
constexpr int EBP = 8192;                          // edges per partition block
constexpr int NPP = (E + EBP - 1) / EBP;           // 196 partition blocks (1024 thr each)
constexpr int PREP_BLKS = 32;                      // weight-prep blocks (W1 only, 8192 entries)
constexpr int MB_BLKS = (M + 255) / 256;           // 20 maskbit blocks

typedef __attribute__((ext_vector_type(8))) short bf16x8;
typedef __attribute__((ext_vector_type(4))) float f32x4;

// ---------------- bf16 helpers (RNE pack, cheap unpack) ----------------

__device__ __forceinline__ unsigned int pack_bf16x2(float a, float b) {
    unsigned int ua = __float_as_uint(a);
    unsigned int ub = __float_as_uint(b);
    ua = (ua + 0x7FFFu + ((ua >> 16) & 1u)) >> 16;
    ub = (ub + 0x7FFFu + ((ub >> 16) & 1u)) & 0xFFFF0000u;
    return ua | ub;
}
__device__ __forceinline__ unsigned short bf16_rne(float a) {
    unsigned int ua = __float_as_uint(a);
    return (unsigned short)((ua + 0x7FFFu + ((ua >> 16) & 1u)) >> 16);
}
__device__ __forceinline__ float bf16_lo(unsigned int u) { return __uint_as_float(u << 16); }
__device__ __forceinline__ float bf16_hi(unsigned int u) { return __uint_as_float(u & 0xFFFF0000u); }

// ---------------- misc1: bucket hist (LDS + global atomics) + W1 prep + maskbit ----------------

__global__ __launch_bounds__(256) void k_misc1(const int* __restrict__ dst,
                                               int* __restrict__ bucketCnt,
                                               const float* __restrict__ W1,
                                               unsigned int* __restrict__ Wt1,
                                               const int* __restrict__ mask,
                                               unsigned int* __restrict__ maskbit,
                                               unsigned int* __restrict__ needed) {
    __shared__ int h[NB];
    const int t = threadIdx.x;
    if (blockIdx.x < NPB) {
        for (int i = t; i < NB; i += 256) h[i] = 0;
        __syncthreads();
        const int base = blockIdx.x * EB;
#pragma unroll
        for (int i = 0; i < 8; ++i) {
            int e = base + t + i * 256;
            if (e < E) {
                int b = __builtin_nontemporal_load(dst + e) >> NBITS;
                atomicAdd(&h[b], 1);
            }
        }
        __syncthreads();
        for (int i = t; i < NB; i += 256) {
            int c = h[i];
            if (c) atomicAdd(&bucketCnt[i], c);
        }
    } else if (blockIdx.x < NPB + PREP_BLKS) {
        int idx = (blockIdx.x - NPB) * 256 + t;   // 8192 total (W1 only; W2 used in fp32)
        int n = idx >> 6, kk = idx & 63;
        float a = W1[(2 * kk) * D + n];
        float b = W1[(2 * kk + 1) * D + n];
        Wt1[idx] = pack_bf16x2(a, b);
    } else {
        int i = (blockIdx.x - NPB - PREP_BLKS) * 256 + t;
        if (i < M) {
            int n = mask[i];
            atomicOr(&maskbit[n >> 5], 1u << (n & 31));
            atomicOr(&needed[n >> 5], 1u << (n & 31));  // masked nodes need their own row
        }
    }
}

// ---------------- misc2: bucket scan (1 block) + needed-set edge scan (NPB blocks) ----------------

__global__ __launch_bounds__(256) void k_misc2(const int* __restrict__ bucketCnt,
                                               int* __restrict__ bucketBase,
                                               int* __restrict__ gCursor,
                                               const unsigned int* __restrict__ maskbit,
                                               const int* __restrict__ src,
                                               const int* __restrict__ dst,
                                               unsigned int* __restrict__ needed) {
    const int t = threadIdx.x;
    if (blockIdx.x == 0) {
        // exclusive scan of bucketCnt[0..NB) -> bucketBase[0..NB]; copy to gCursor.
        __shared__ int waveS[4];
        const int lane = t & 63, wave = t >> 6;
        const int idx = t * 4;
        int c[4];
        int s = 0;
#pragma unroll
        for (int g = 0; g < 4; ++g) {
            c[g] = (idx + g < NB) ? bucketCnt[idx + g] : 0;
            s += c[g];
        }
        int v = s;
        for (int off = 1; off < 64; off <<= 1) {
            int u = __shfl_up(v, off);
            if (lane >= off) v += u;
        }
        if (lane == 63) waveS[wave] = v;
        __syncthreads();
        int wb = 0;
        for (int w = 0; w < 4; ++w) if (w < wave) wb += waveS[w];
        int run = wb + v - s;   // exclusive prefix
#pragma unroll
        for (int g = 0; g < 4; ++g) {
            int pos = idx + g;
            if (pos < NB) {
                bucketBase[pos] = run;
                gCursor[pos] = run;
            }
            run += c[g];
        }
        if (t == 255) bucketBase[NB] = E;
    } else {
        const int base = (blockIdx.x - 1) * EB;
#pragma unroll
        for (int i = 0; i < 8; ++i) {
            int e = base + t + i * 256;
            if (e < E) {
                int d = __builtin_nontemporal_load(dst + e);
                if ((maskbit[d >> 5] >> (d & 31)) & 1u) {
                    int s = src[e];
                    atomicOr(&needed[s >> 5], 1u << (s & 31));
                }
            }
        }
    }
}

// ---------------- partition: register-stash + atomic run reservation ----------------
// record: bits[6:0]=d&127, bits[26:7]=src, bits[63:32]=ew bits

__global__ __launch_bounds__(1024) void k_part(const int* __restrict__ src,
                                               const int* __restrict__ dst,
                                               const float* __restrict__ ew,
                                               int* __restrict__ gCursor,
                                               unsigned long long* __restrict__ tmp) {
    __shared__ int cnt[NB];
    __shared__ int off[NB];
    __shared__ int rk[NB];
    const int t = threadIdx.x;
    for (int i = t; i < NB; i += 1024) { cnt[i] = 0; rk[i] = 0; }
    __syncthreads();

    const int eb = blockIdx.x * EBP;
    int d_[8], s_[8];
    float w_[8];
#pragma unroll
    for (int i = 0; i < 8; ++i) {
        int e = eb + t + i * 1024;
        if (e < E) {
            d_[i] = __builtin_nontemporal_load(dst + e);
            s_[i] = __builtin_nontemporal_load(src + e);
            w_[i] = __builtin_nontemporal_load(ew + e);
            atomicAdd(&cnt[d_[i] >> NBITS], 1);
        } else {
            d_[i] = -1;
        }
    }
    __syncthreads();

    for (int i = t; i < NB; i += 1024) {
        int c = cnt[i];
        if (c > 0) off[i] = atomicAdd(&gCursor[i], c);
    }
    __syncthreads();

#pragma unroll
    for (int i = 0; i < 8; ++i) {
        if (d_[i] >= 0) {
            int b = d_[i] >> NBITS;
            int r = atomicAdd(&rk[b], 1);
            unsigned long long rec =
                ((unsigned long long)(unsigned int)__float_as_int(w_[i]) << 32) |
                ((unsigned int)s_[i] << NBITS) | (unsigned int)(d_[i] & (BUCKET - 1));
            tmp[(size_t)off[b] + r] = rec;   // cached store: L2 merges the ~84B runs
        }
    }
}

// ---------------- shared-memory union: GEMM W-tile OR local-sort arrays ----------------

union SMem {
    unsigned int Ws[128 * 68];
    struct { int cnt[BUCKET]; float wsum[BUCKET]; int off[BUCKET]; int waveS[2]; } l;
};

// ---------------- MFMA GEMM body: 256 rows/block, 4 waves; wave = 64 rows x 128 cols ----------------
// A-frag: A[m=lane&15][k=quad*8+j]; B-frag: B[k=quad*8+j][n=lane&15];
// D: col=lane&15, row=quad*4+reg  (HW-verified layouts, 16x16x32 bf16).
// W^T staged in LDS with 68-uint row stride (bank-conflict padding).

template <bool BF16IN>
__device__ __forceinline__ void gemm_mfma_body(unsigned int* __restrict__ Ws,
                                               const void* __restrict__ Xin,
                                               const unsigned int* __restrict__ Wt,
                                               unsigned short* __restrict__ out, int blk) {
    const int t = threadIdx.x;
#pragma unroll
    for (int i = 0; i < 8; ++i) {
        int f4 = t + i * 256;        // uint4 index, 2048 total
        int n = f4 >> 4;
        int k4 = f4 & 15;
        uint4 w = ((const uint4*)Wt)[f4];
        *(uint4*)(&Ws[n * 68 + k4 * 4]) = w;
    }
    __syncthreads();

    const int wv = t >> 6, lane = t & 63;
    const int q = lane >> 4, l15 = lane & 15;
    const int rowBase = blk * 256 + wv * 64;

    f32x4 acc[4][8] = {};
#pragma unroll
    for (int kc = 0; kc < 4; ++kc) {
        bf16x8 af[4];
#pragma unroll
        for (int rt = 0; rt < 4; ++rt) {
            int row = rowBase + rt * 16 + l15;
            if (row > N - 1) row = N - 1;   // tail: duplicate last row, stores guarded
            union { uint4 u; bf16x8 v; } cv;
            if (BF16IN) {
                cv.u = *(const uint4*)((const unsigned int*)Xin + (size_t)row * 64 + kc * 16 + q * 4);
            } else {
                const float* xr = (const float*)Xin + (size_t)row * D + kc * 32 + q * 8;
                float4 x0 = *(const float4*)xr;
                float4 x1 = *(const float4*)(xr + 4);
                cv.u.x = pack_bf16x2(x0.x, x0.y);
                cv.u.y = pack_bf16x2(x0.z, x0.w);
                cv.u.z = pack_bf16x2(x1.x, x1.y);
                cv.u.w = pack_bf16x2(x1.z, x1.w);
            }
            af[rt] = cv.v;
        }
#pragma unroll
        for (int ct = 0; ct < 8; ++ct) {
            union { uint4 u; bf16x8 v; } bv;
            bv.u = *(const uint4*)(&Ws[(ct * 16 + l15) * 68 + kc * 16 + q * 4]);
#pragma unroll
            for (int rt = 0; rt < 4; ++rt)
                acc[rt][ct] = __builtin_amdgcn_mfma_f32_16x16x32_bf16(af[rt], bv.v, acc[rt][ct], 0, 0, 0);
        }
    }

#pragma unroll
    for (int rt = 0; rt < 4; ++rt) {
#pragma unroll
        for (int ct = 0; ct < 8; ++ct) {
            int col = ct * 16 + l15;
#pragma unroll
            for (int r = 0; r < 4; ++r) {
                int row = rowBase + rt * 16 + q * 4 + r;
                if (row < N) out[(size_t)row * D + col] = bf16_rne(acc[rt][ct][r]);
            }
        }
    }
}

// ---- local pass-A: per-bucket counts -> rowStart, dis, cursors (offG). No pairs scatter. ----

__device__ __forceinline__ void local_a_body(SMem& sm,
                                             const unsigned long long* __restrict__ tmp,
                                             const int* __restrict__ bucketBase,
                                             float* __restrict__ dis,
                                             int* __restrict__ rowStart,
                                             int* __restrict__ offG) {
    const int b = blockIdx.x;
    const int t = threadIdx.x;
    const int segBeg = bucketBase[b];
    const int segEnd = bucketBase[b + 1];

    int*   cnt   = sm.l.cnt;
    float* wsum  = sm.l.wsum;
    int*   waveS = sm.l.waveS;
    if (t < BUCKET) { cnt[t] = 0; wsum[t] = 0.f; }
    __syncthreads();

    for (int e = segBeg + t; e < segEnd; e += 256) {
        unsigned long long rec = tmp[e];
        int dl = (int)(rec & (BUCKET - 1));
        float w = __uint_as_float((unsigned int)(rec >> 32));
        atomicAdd(&cnt[dl], 1);
        atomicAdd(&wsum[dl], w);
    }
    __syncthreads();

    const int lane = t & 63, wv = t >> 6;
    const int pv = (t < BUCKET) ? cnt[t] : 0;
    int v = pv;
    for (int o = 1; o < 64; o <<= 1) {
        int u = __shfl_up(v, o);
        if (lane >= o) v += u;
    }
    if (lane == 63 && wv < 2) waveS[wv] = v;
    __syncthreads();
    if (t < BUCKET) {
        const int wb = (wv == 1) ? waveS[0] : 0;
        const int ex = wb + v - pv;
        offG[b * BUCKET + t] = ex;
        const int node = b * BUCKET + t;
        if (node < N) { rowStart[node] = segBeg + ex; dis[node] = rsqrtf(1.0f + wsum[t]); }
    }
    if (b == NB - 1 && t == 0) rowStart[N] = E;
}

// ---------------- fused: local pass-A (blocks 0..NB) + GEMM1 A=x@W1 (blocks NB..) ----

__global__ __launch_bounds__(256) void k_local_g1(const unsigned long long* __restrict__ tmp,
                                                  const int* __restrict__ bucketBase,
                                                  float* __restrict__ dis,
                                                  int* __restrict__ rowStart,
                                                  int* __restrict__ offG,
                                                  const float* __restrict__ x,
                                                  const unsigned int* __restrict__ Wt1,
                                                  unsigned short* __restrict__ A) {
    __shared__ SMem sm;
    if (blockIdx.x < NB) {
        local_a_body(sm, tmp, bucketBase, dis, rowStart, offG);
    } else {
        gemm_mfma_body<false>(sm.Ws, x, Wt1, A, blockIdx.x - NB);
    }
}

// ---- local pass-B: scatter node-sorted pairs with PRE-MULTIPLIED v = ew*dis[src]. ----
// dis is globally complete here (kernel boundary). The dis[src] lookup is a per-thread
// gather: ONE instruction covers 64 edges, vs one broadcast load per edge if done in
// the aggregate kernels. pairs: (src, f32bits of ew*dis[src]).

__global__ __launch_bounds__(256) void k_local_b(const unsigned long long* __restrict__ tmp,
                                                 const int* __restrict__ bucketBase,
                                                 const int* __restrict__ offG,
                                                 const float* __restrict__ dis,
                                                 int2* __restrict__ pairs) {
    __shared__ int cnt[BUCKET];
    __shared__ int off[BUCKET];
    const int b = blockIdx.x;
    const int t = threadIdx.x;
    if (t < BUCKET) { cnt[t] = 0; off[t] = offG[b * BUCKET + t]; }
    __syncthreads();
    const int segBeg = bucketBase[b];
    const int segEnd = bucketBase[b + 1];
    for (int e = segBeg + t; e < segEnd; e += 256) {
        unsigned long long rec = tmp[e];
        int dl = (int)(rec & (BUCKET - 1));
        int s  = (int)((rec >> NBITS) & 0xFFFFF);
        float w = __uint_as_float((unsigned int)(rec >> 32));
        float v = w * dis[s];
        int r = atomicAdd(&cnt[dl], 1);
        pairs[segBeg + off[dl] + r] = make_int2(s, __float_as_int(v));
    }
}

// ---------------- aggregate layer 1 (needed nodes only): B = relu(dis*sum + A/deg + b1) ----------------
// One wave per node; lane owns a col-pair. 8-deep gather group (R4 lesson: 16-deep
// exceeds the VGPR grant -> compiler serializes; 8-deep @ VGPR~32 was the sweet spot).
// pairs.y already holds ew*dis[src] -> 2 vmem per edge instead of 3.

__global__ __launch_bounds__(256) void k_aggregate(const unsigned int* __restrict__ Hb,
                                                   const int2* __restrict__ pairs,
                                                   const int* __restrict__ rowStart,
                                                   const float* __restrict__ dis,
                                                   const unsigned int* __restrict__ needed,
                                                   const float* __restrict__ b,
                                                   unsigned int* __restrict__ outB) {
    int node = blockIdx.x * 4 + (threadIdx.x >> 6);
    if (node >= N) return;
    if (!((needed[node >> 5] >> (node & 31)) & 1u)) return;  // row never consumed downstream
    int lane = threadIdx.x & 63;
    int beg = rowStart[node], end = rowStart[node + 1];

    float ax = 0.f, ay = 0.f;
    int j = beg;
    for (; j + 7 < end; j += 8) {
        int2 p[8];
        unsigned int h[8];
#pragma unroll
        for (int i = 0; i < 8; ++i) p[i] = pairs[j + i];
#pragma unroll
        for (int i = 0; i < 8; ++i) h[i] = Hb[(size_t)p[i].x * 64 + lane];
#pragma unroll
        for (int i = 0; i < 8; ++i) {
            float v = __int_as_float(p[i].y);
            ax += bf16_lo(h[i]) * v;
            ay += bf16_hi(h[i]) * v;
        }
    }
    for (; j + 3 < end; j += 4) {
        int2 p[4];
        unsigned int h[4];
#pragma unroll
        for (int i = 0; i < 4; ++i) p[i] = pairs[j + i];
#pragma unroll
        for (int i = 0; i < 4; ++i) h[i] = Hb[(size_t)p[i].x * 64 + lane];
#pragma unroll
        for (int i = 0; i < 4; ++i) {
            float v = __int_as_float(p[i].y);
            ax += bf16_lo(h[i]) * v;
            ay += bf16_hi(h[i]) * v;
        }
    }
    for (; j < end; ++j) {
        int2 p0 = pairs[j];
        unsigned int h0 = Hb[(size_t)p0.x * 64 + lane];
        float v0 = __int_as_float(p0.y);
        ax += bf16_lo(h0) * v0;
        ay += bf16_hi(h0) * v0;
    }

    float dd = dis[node];
    float sn = dd * dd;  // self-loop norm = 1/deg
    unsigned int hs = Hb[(size_t)node * 64 + lane];
    float2 bb = ((const float2*)b)[lane];
    float ox = fmaxf(ax * dd + bf16_lo(hs) * sn + bb.x, 0.f);
    float oy = fmaxf(ay * dd + bf16_hi(hs) * sn + bb.y, 0.f);
    __builtin_nontemporal_store(pack_bf16x2(ox, oy), outB + (size_t)node * 64 + lane);
}

// ---------------- layer-2: aggregation is LINEAR, so agg(B@W2) = agg(B)@W2. ----------------
// Aggregate B at mask nodes (fp32, no bias) -> aggB [M x 128], then a tiny fp32 GEMM
// aggB@W2 + b2 -> out. (R4: killed the full-N k_gemm2.)

__global__ __launch_bounds__(256) void k_agg_mask_B(const unsigned int* __restrict__ Hb,
                                                    const int2* __restrict__ pairs,
                                                    const int* __restrict__ rowStart,
                                                    const float* __restrict__ dis,
                                                    const int* __restrict__ mask,
                                                    const int* __restrict__ y,
                                                    float* __restrict__ aggB,
                                                    float* __restrict__ out) {
    int i = blockIdx.x * 4 + (threadIdx.x >> 6);
    if (i >= M) return;
    int lane = threadIdx.x & 63;
    int node = mask[i];
    int beg = rowStart[node], end = rowStart[node + 1];

    float ax = 0.f, ay = 0.f;
    int j = beg;
    for (; j + 7 < end; j += 8) {
        int2 p[8];
        unsigned int h[8];
#pragma unroll
        for (int ii = 0; ii < 8; ++ii) p[ii] = pairs[j + ii];
#pragma unroll
        for (int ii = 0; ii < 8; ++ii) h[ii] = Hb[(size_t)p[ii].x * 64 + lane];
#pragma unroll
        for (int ii = 0; ii < 8; ++ii) {
            float v = __int_as_float(p[ii].y);
            ax += bf16_lo(h[ii]) * v;
            ay += bf16_hi(h[ii]) * v;
        }
    }
    for (; j < end; ++j) {
        int2 p0 = pairs[j];
        unsigned int h0 = Hb[(size_t)p0.x * 64 + lane];
        float v0 = __int_as_float(p0.y);
        ax += bf16_lo(h0) * v0;
        ay += bf16_hi(h0) * v0;
    }

    float dd = dis[node];
    float sn = dd * dd;
    unsigned int hs = Hb[(size_t)node * 64 + lane];
    float ox = ax * dd + bf16_lo(hs) * sn;   // NO bias here; b2 added after the GEMM
    float oy = ay * dd + bf16_hi(hs) * sn;
    ((float2*)(aggB + (size_t)i * D))[lane] = make_float2(ox, oy);
    if (lane == 0) out[(size_t)M * D + i] = (float)y[node];
}

// ---- out = aggB @ W2 + b2, all fp32. 4 rows/block; W2 (64KB) staged in LDS. ----

__global__ __launch_bounds__(256) void k_out_gemm(const float* __restrict__ aggB,
                                                  const float* __restrict__ W2,
                                                  const float* __restrict__ b2,
                                                  float* __restrict__ out) {
    __shared__ float w2s[128 * 132];   // pad 132: 16B-aligned float4 stores, bank spread
    __shared__ float rowL[4][128];
    const int t = threadIdx.x;
    const int wv = t >> 6, lane = t & 63;
    const int row = blockIdx.x * 4 + wv;   // grid = M/4 exactly (1250*4 = 5000)

    for (int i = t; i < 4096; i += 256) {
        float4 v = ((const float4*)W2)[i];
        int k = (4 * i) >> 7, n = (4 * i) & 127;
        *(float4*)(&w2s[k * 132 + n]) = v;
    }
    float2 a2 = ((const float2*)(aggB + (size_t)row * D))[lane];
    rowL[wv][2 * lane] = a2.x;
    rowL[wv][2 * lane + 1] = a2.y;
    __syncthreads();

    float2 bb = ((const float2*)b2)[lane];
    float acc0 = bb.x, acc1 = bb.y;
#pragma unroll 8
    for (int k = 0; k < 128; ++k) {
        float a = rowL[wv][k];
        float2 w = *(const float2*)(&w2s[k * 132 + 2 * lane]);
        acc0 += a * w.x;
        acc1 += a * w.y;
    }
    ((float2*)(out + (size_t)row * D))[lane] = make_float2(acc0, acc1);
}

extern "C" void kernel_launch(void* const* d_in, const int* in_sizes, int n_in,
                              void* d_out, int out_size, void* d_ws, size_t ws_size,
                              hipStream_t stream) {
    const float* x  = (const float*)d_in[0];
    const float* ew = (const float*)d_in[1];
    const float* W1 = (const float*)d_in[2];
    const float* b1 = (const float*)d_in[3];
    const float* W2 = (const float*)d_in[4];
    const float* b2 = (const float*)d_in[5];
    const int* eidx = (const int*)d_in[6];
    const int* mask = (const int*)d_in[7];
    const int* y    = (const int*)d_in[8];
    const int* src = eidx;       // edge_index[0]
    const int* dst = eidx + E;   // edge_index[1]

    // Workspace layout (bytes):
    //   dis        @ 0       : N f32       (0.4 MB)
    //   rowStart   @ 512 KB  : N+1 i32     (0.4 MB)
    //   maskbit    @ 960 KB  : 16 KB bitmap }
    //   needed     @ 976 KB  : 16 KB bitmap }  zeroed together (40 KB memset)
    //   bucketCnt  @ 992 KB  : NB i32
    //   bucketBase @ 996 KB  : NB+1 i32
    //   gCursor    @ 1000 KB : NB i32
    //   Wt1        @ 1008 KB : 8192 u32   (32 KB)
    //   offG       @ 1040 KB : NB*128 i32 (400 KB)
    //   pairs      @ 2 MB    : E int2     (12.8 MB)
    //   tmp        @ 16 MB   : E u64      (12.8 MB)
    //   A  (bf16)  @ 29 MB   : N*D bf16   (25.6 MB)
    //   B  (bf16)  @ 55 MB   : N*D bf16   (25.6 MB)
    //   aggB (f32) @ 81 MB   : M*D f32    (2.56 MB)   total ~84 MB
    char* ws = (char*)d_ws;
    float* dis      = (float*)(ws);
    int*   rowStart = (int*)(ws + (size_t)512 * 1024);
    unsigned int* maskbit = (unsigned int*)(ws + (size_t)960 * 1024);
    unsigned int* needed  = (unsigned int*)(ws + (size_t)976 * 1024);
    int*   bucketCnt  = (int*)(ws + (size_t)992 * 1024);
    int*   bucketBase = (int*)(ws + (size_t)996 * 1024);
    int*   gCursor    = (int*)(ws + (size_t)1000 * 1024);
    unsigned int* Wt1 = (unsigned int*)(ws + (size_t)1008 * 1024);
    int*   offG     = (int*)(ws + (size_t)1040 * 1024);
    int2*  pairs    = (int2*)(ws + (size_t)2 * 1024 * 1024);
    unsigned long long* tmp = (unsigned long long*)(ws + (size_t)16 * 1024 * 1024);
    unsigned short* A  = (unsigned short*)(ws + (size_t)29 * 1024 * 1024);
    unsigned short* B  = (unsigned short*)(ws + (size_t)55 * 1024 * 1024);
    float* aggB = (float*)(ws + (size_t)81 * 1024 * 1024);

    // --- zero bitmaps + bucket counters, then fused hist + W1 prep + maskbit ---
    (void)hipMemsetAsync(ws + (size_t)960 * 1024, 0, (size_t)40 * 1024, stream);
    hipLaunchKernelGGL(k_misc1, dim3(NPB + PREP_BLKS + MB_BLKS), dim3(256), 0, stream,
                       dst, bucketCnt, W1, Wt1, mask, maskbit, needed);

    // --- bucket scan (1 block) + needed-set edge scan ---
    hipLaunchKernelGGL(k_misc2, dim3(1 + NPB), dim3(256), 0, stream,
                       bucketCnt, bucketBase, gCursor, maskbit, src, dst, needed);

    // --- partition via atomic run reservation ---
    hipLaunchKernelGGL(k_part, dim3(NPP), dim3(1024), 0, stream,
                       src, dst, ew, gCursor, tmp);

    // --- local pass-A (rowStart, dis, cursors) fused with GEMM1 ---
    hipLaunchKernelGGL(k_local_g1, dim3(NB + MF_BLKS), dim3(256), 0, stream,
                       tmp, bucketBase, dis, rowStart, offG, x, Wt1, A);

    // --- local pass-B: pairs with pre-multiplied ew*dis[src] ---
    hipLaunchKernelGGL(k_local_b, dim3(NB), dim3(256), 0, stream,
                       tmp, bucketBase, offG, dis, pairs);

    // --- layer 1 aggregate at needed nodes only: B = relu(agg(A) + b1) ---
    hipLaunchKernelGGL(k_aggregate, dim3((N + 3) / 4), dim3(256), 0, stream,
                       (const unsigned int*)A, pairs, rowStart, dis, needed, b1,
                       (unsigned int*)B);

    // --- layer 2 (linearity): aggB = agg(B) at mask nodes; out = aggB@W2 + b2 ---
    hipLaunchKernelGGL(k_agg_mask_B, dim3((M + 3) / 4), dim3(256), 0, stream,
                       (const unsigned int*)B, pairs, rowStart, dis, mask, y,
                       aggB, (float*)d_out);
    hipLaunchKernelGGL(k_out_gemm, dim3(M / 4), dim3(256), 0, stream,
                       aggB, W2, b2, (float*)d_out);
}

// Round 6
// 276.047 us; speedup vs baseline: 1.0954x; 1.0404x over previous
//
#include <hip/hip_runtime.h>

// Problem constants (fixed by the reference).
constexpr int N = 100000;   // nodes
constexpr int E = 1600000;  // edges
constexpr int D = 128;      // feature dim (both layers)
constexpr int M = 5000;     // mask size

constexpr int MF_BLKS = (N + 255) / 256;           // 391 mfma-gemm blocks (256 rows each)

// Counting-sort CSR build parameters.
// Bucket = dst>>7 (128 nodes) -> 782 buckets.
// k_part: atomic run-reservation (R3: killed the 3.84x write amp).
// k_sort_agg (R6): local sort kept in LDS and aggregation fused behind it --
// pairs cross the kernel boundary only for the small mask pass.
constexpr int NBITS = 7;
constexpr int BUCKET = 1 << NBITS;                 // 128 nodes per bucket
constexpr int NB  = (N + BUCKET - 1) / BUCKET;     // 782 buckets
constexpr int EB  = 2048;                          // edges per hist/needed-scan block
constexpr int NPB = (E + EB - 1) / EB;             // 782 hist / needed-scan blocks
constexpr int EBP = 8192;                          // edges per partition block
constexpr int NPP = (E + EBP - 1) / EBP;           // 196 partition blocks (1024 thr each)
constexpr int PREP_BLKS = 32;                      // weight-prep blocks (W1 only)
constexpr int MB_BLKS = (M + 255) / 256;           // 20 maskbit blocks
constexpr int CAP = 3072;                          // LDS pair capacity per bucket
                                                   // (bucket counts ~Poisson(2046), max ~2.3K)

typedef __attribute__((ext_vector_type(8))) short bf16x8;
typedef __attribute__((ext_vector_type(4))) float f32x4;

// ---------------- bf16 helpers (RNE pack, cheap unpack) ----------------

__device__ __forceinline__ unsigned int pack_bf16x2(float a, float b) {
    unsigned int ua = __float_as_uint(a);
    unsigned int ub = __float_as_uint(b);
    ua = (ua + 0x7FFFu + ((ua >> 16) & 1u)) >> 16;
    ub = (ub + 0x7FFFu + ((ub >> 16) & 1u)) & 0xFFFF0000u;
    return ua | ub;
}
__device__ __forceinline__ unsigned short bf16_rne(float a) {
    unsigned int ua = __float_as_uint(a);
    return (unsigned short)((ua + 0x7FFFu + ((ua >> 16) & 1u)) >> 16);
}
__device__ __forceinline__ float bf16_lo(unsigned int u) { return __uint_as_float(u << 16); }
__device__ __forceinline__ float bf16_hi(unsigned int u) { return __uint_as_float(u & 0xFFFF0000u); }

// ---------------- misc1: bucket hist (LDS + global atomics) + W1 prep + maskbit ----------------

__global__ __launch_bounds__(256) void k_misc1(const int* __restrict__ dst,
                                               int* __restrict__ bucketCnt,
                                               const float* __restrict__ W1,
                                               unsigned int* __restrict__ Wt1,
                                               const int* __restrict__ mask,
                                               unsigned int* __restrict__ maskbit,
                                               unsigned int* __restrict__ needed) {
    __shared__ int h[NB];
    const int t = threadIdx.x;
    if (blockIdx.x < NPB) {
        for (int i = t; i < NB; i += 256) h[i] = 0;
        __syncthreads();
        const int base = blockIdx.x * EB;
#pragma unroll
        for (int i = 0; i < 8; ++i) {
            int e = base + t + i * 256;
            if (e < E) {
                int b = __builtin_nontemporal_load(dst + e) >> NBITS;
                atomicAdd(&h[b], 1);
            }
        }
        __syncthreads();
        for (int i = t; i < NB; i += 256) {
            int c = h[i];
            if (c) atomicAdd(&bucketCnt[i], c);
        }
    } else if (blockIdx.x < NPB + PREP_BLKS) {
        int idx = (blockIdx.x - NPB) * 256 + t;   // 8192 total (W1 only; W2 used in fp32)
        int n = idx >> 6, kk = idx & 63;
        float a = W1[(2 * kk) * D + n];
        float b = W1[(2 * kk + 1) * D + n];
        Wt1[idx] = pack_bf16x2(a, b);
    } else {
        int i = (blockIdx.x - NPB - PREP_BLKS) * 256 + t;
        if (i < M) {
            int n = mask[i];
            atomicOr(&maskbit[n >> 5], 1u << (n & 31));
            atomicOr(&needed[n >> 5], 1u << (n & 31));  // masked nodes need their own row
        }
    }
}

// ---------------- misc2: bucket scan (1 block) + needed-set edge scan (NPB blocks) ----------------

__global__ __launch_bounds__(256) void k_misc2(const int* __restrict__ bucketCnt,
                                               int* __restrict__ bucketBase,
                                               int* __restrict__ gCursor,
                                               const unsigned int* __restrict__ maskbit,
                                               const int* __restrict__ src,
                                               const int* __restrict__ dst,
                                               unsigned int* __restrict__ needed) {
    const int t = threadIdx.x;
    if (blockIdx.x == 0) {
        // exclusive scan of bucketCnt[0..NB) -> bucketBase[0..NB]; copy to gCursor.
        __shared__ int waveS[4];
        const int lane = t & 63, wave = t >> 6;
        const int idx = t * 4;
        int c[4];
        int s = 0;
#pragma unroll
        for (int g = 0; g < 4; ++g) {
            c[g] = (idx + g < NB) ? bucketCnt[idx + g] : 0;
            s += c[g];
        }
        int v = s;
        for (int off = 1; off < 64; off <<= 1) {
            int u = __shfl_up(v, off);
            if (lane >= off) v += u;
        }
        if (lane == 63) waveS[wave] = v;
        __syncthreads();
        int wb = 0;
        for (int w = 0; w < 4; ++w) if (w < wave) wb += waveS[w];
        int run = wb + v - s;   // exclusive prefix
#pragma unroll
        for (int g = 0; g < 4; ++g) {
            int pos = idx + g;
            if (pos < NB) {
                bucketBase[pos] = run;
                gCursor[pos] = run;
            }
            run += c[g];
        }
        if (t == 255) bucketBase[NB] = E;
    } else {
        const int base = (blockIdx.x - 1) * EB;
#pragma unroll
        for (int i = 0; i < 8; ++i) {
            int e = base + t + i * 256;
            if (e < E) {
                int d = __builtin_nontemporal_load(dst + e);
                if ((maskbit[d >> 5] >> (d & 31)) & 1u) {
                    int s = src[e];
                    atomicOr(&needed[s >> 5], 1u << (s & 31));
                }
            }
        }
    }
}

// ---------------- partition: register-stash + atomic run reservation ----------------
// record: bits[6:0]=d&127, bits[26:7]=src, bits[63:32]=ew bits

__global__ __launch_bounds__(1024) void k_part(const int* __restrict__ src,
                                               const int* __restrict__ dst,
                                               const float* __restrict__ ew,
                                               int* __restrict__ gCursor,
                                               unsigned long long* __restrict__ tmp) {
    __shared__ int cnt[NB];
    __shared__ int off[NB];
    __shared__ int rk[NB];
    const int t = threadIdx.x;
    for (int i = t; i < NB; i += 1024) { cnt[i] = 0; rk[i] = 0; }
    __syncthreads();

    const int eb = blockIdx.x * EBP;
    int d_[8], s_[8];
    float w_[8];
#pragma unroll
    for (int i = 0; i < 8; ++i) {
        int e = eb + t + i * 1024;
        if (e < E) {
            d_[i] = __builtin_nontemporal_load(dst + e);
            s_[i] = __builtin_nontemporal_load(src + e);
            w_[i] = __builtin_nontemporal_load(ew + e);
            atomicAdd(&cnt[d_[i] >> NBITS], 1);
        } else {
            d_[i] = -1;
        }
    }
    __syncthreads();

    for (int i = t; i < NB; i += 1024) {
        int c = cnt[i];
        if (c > 0) off[i] = atomicAdd(&gCursor[i], c);
    }
    __syncthreads();

#pragma unroll
    for (int i = 0; i < 8; ++i) {
        if (d_[i] >= 0) {
            int b = d_[i] >> NBITS;
            int r = atomicAdd(&rk[b], 1);
            unsigned long long rec =
                ((unsigned long long)(unsigned int)__float_as_int(w_[i]) << 32) |
                ((unsigned int)s_[i] << NBITS) | (unsigned int)(d_[i] & (BUCKET - 1));
            tmp[(size_t)off[b] + r] = rec;   // cached store: L2 merges the ~84B runs
        }
    }
}

// ---------------- shared-memory union: GEMM W-tile OR local-sort arrays ----------------

union SMem {
    unsigned int Ws[128 * 68];
    struct { int cnt[BUCKET]; float wsum[BUCKET]; int waveS[2]; } l;
};

// ---------------- MFMA GEMM body: 256 rows/block, 4 waves; wave = 64 rows x 128 cols ----------------
// A-frag: A[m=lane&15][k=quad*8+j]; B-frag: B[k=quad*8+j][n=lane&15];
// D: col=lane&15, row=quad*4+reg  (HW-verified layouts, 16x16x32 bf16).
// W^T staged in LDS with 68-uint row stride (bank-conflict padding).

template <bool BF16IN>
__device__ __forceinline__ void gemm_mfma_body(unsigned int* __restrict__ Ws,
                                               const void* __restrict__ Xin,
                                               const unsigned int* __restrict__ Wt,
                                               unsigned short* __restrict__ out, int blk) {
    const int t = threadIdx.x;
#pragma unroll
    for (int i = 0; i < 8; ++i) {
        int f4 = t + i * 256;        // uint4 index, 2048 total
        int n = f4 >> 4;
        int k4 = f4 & 15;
        uint4 w = ((const uint4*)Wt)[f4];
        *(uint4*)(&Ws[n * 68 + k4 * 4]) = w;
    }
    __syncthreads();

    const int wv = t >> 6, lane = t & 63;
    const int q = lane >> 4, l15 = lane & 15;
    const int rowBase = blk * 256 + wv * 64;

    f32x4 acc[4][8] = {};
#pragma unroll
    for (int kc = 0; kc < 4; ++kc) {
        bf16x8 af[4];
#pragma unroll
        for (int rt = 0; rt < 4; ++rt) {
            int row = rowBase + rt * 16 + l15;
            if (row > N - 1) row = N - 1;   // tail: duplicate last row, stores guarded
            union { uint4 u; bf16x8 v; } cv;
            if (BF16IN) {
                cv.u = *(const uint4*)((const unsigned int*)Xin + (size_t)row * 64 + kc * 16 + q * 4);
            } else {
                const float* xr = (const float*)Xin + (size_t)row * D + kc * 32 + q * 8;
                float4 x0 = *(const float4*)xr;
                float4 x1 = *(const float4*)(xr + 4);
                cv.u.x = pack_bf16x2(x0.x, x0.y);
                cv.u.y = pack_bf16x2(x0.z, x0.w);
                cv.u.z = pack_bf16x2(x1.x, x1.y);
                cv.u.w = pack_bf16x2(x1.z, x1.w);
            }
            af[rt] = cv.v;
        }
#pragma unroll
        for (int ct = 0; ct < 8; ++ct) {
            union { uint4 u; bf16x8 v; } bv;
            bv.u = *(const uint4*)(&Ws[(ct * 16 + l15) * 68 + kc * 16 + q * 4]);
#pragma unroll
            for (int rt = 0; rt < 4; ++rt)
                acc[rt][ct] = __builtin_amdgcn_mfma_f32_16x16x32_bf16(af[rt], bv.v, acc[rt][ct], 0, 0, 0);
        }
    }

#pragma unroll
    for (int rt = 0; rt < 4; ++rt) {
#pragma unroll
        for (int ct = 0; ct < 8; ++ct) {
            int col = ct * 16 + l15;
#pragma unroll
            for (int r = 0; r < 4; ++r) {
                int row = rowBase + rt * 16 + q * 4 + r;
                if (row < N) out[(size_t)row * D + col] = bf16_rne(acc[rt][ct][r]);
            }
        }
    }
}

// ---- local pass-A: per-bucket counts -> dis + exclusive per-node offsets (offG). ----

__device__ __forceinline__ void local_a_body(SMem& sm,
                                             const unsigned long long* __restrict__ tmp,
                                             const int* __restrict__ bucketBase,
                                             float* __restrict__ dis,
                                             int* __restrict__ offG) {
    const int b = blockIdx.x;
    const int t = threadIdx.x;
    const int segBeg = bucketBase[b];
    const int segEnd = bucketBase[b + 1];

    int*   cnt   = sm.l.cnt;
    float* wsum  = sm.l.wsum;
    int*   waveS = sm.l.waveS;
    if (t < BUCKET) { cnt[t] = 0; wsum[t] = 0.f; }
    __syncthreads();

    for (int e = segBeg + t; e < segEnd; e += 256) {
        unsigned long long rec = tmp[e];
        int dl = (int)(rec & (BUCKET - 1));
        float w = __uint_as_float((unsigned int)(rec >> 32));
        atomicAdd(&cnt[dl], 1);
        atomicAdd(&wsum[dl], w);
    }
    __syncthreads();

    const int lane = t & 63, wv = t >> 6;
    const int pv = (t < BUCKET) ? cnt[t] : 0;
    int v = pv;
    for (int o = 1; o < 64; o <<= 1) {
        int u = __shfl_up(v, o);
        if (lane >= o) v += u;
    }
    if (lane == 63 && wv < 2) waveS[wv] = v;
    __syncthreads();
    if (t < BUCKET) {
        const int wb = (wv == 1) ? waveS[0] : 0;
        const int ex = wb + v - pv;
        offG[b * BUCKET + t] = ex;
        const int node = b * BUCKET + t;
        if (node < N) dis[node] = rsqrtf(1.0f + wsum[t]);
    }
}

// ---------------- fused: local pass-A (blocks 0..NB) + GEMM1 A=x@W1 (blocks NB..) ----

__global__ __launch_bounds__(256) void k_local_g1(const unsigned long long* __restrict__ tmp,
                                                  const int* __restrict__ bucketBase,
                                                  float* __restrict__ dis,
                                                  int* __restrict__ offG,
                                                  const float* __restrict__ x,
                                                  const unsigned int* __restrict__ Wt1,
                                                  unsigned short* __restrict__ A) {
    __shared__ SMem sm;
    if (blockIdx.x < NB) {
        local_a_body(sm, tmp, bucketBase, dis, offG);
    } else {
        gemm_mfma_body<false>(sm.Ws, x, Wt1, A, blockIdx.x - NB);
    }
}

// ---------------- fused sort+aggregate: block (512 thr) per bucket ----------------
// Phase 1: stream tmp segment once; scatter (src, ew*dis[src]) pairs into LDS at the
// node-sorted position (and to global pairs for the later mask pass). Phase 2: each of
// the 8 waves aggregates 16 of the bucket's 128 nodes, pair entries read from LDS
// (wave-uniform broadcast), Hb rows gathered 8-deep. Replaces k_local_b + k_aggregate:
// kills the pairs round-trip (25.6MB) and one launch; 8 waves/block -> ~6 waves/SIMD
// during the gather phase (R5 measured 4.4).

__global__ __launch_bounds__(512) void k_sort_agg(const unsigned long long* __restrict__ tmp,
                                                  const int* __restrict__ bucketBase,
                                                  const int* __restrict__ offG,
                                                  const float* __restrict__ dis,
                                                  const unsigned int* __restrict__ needed,
                                                  const float* __restrict__ b,
                                                  const unsigned int* __restrict__ Hb,
                                                  int* __restrict__ rowStart,
                                                  int2* __restrict__ pairs,
                                                  unsigned int* __restrict__ outB) {
    __shared__ int2 lp[CAP];
    __shared__ int cnt[BUCKET];
    __shared__ int offL[BUCKET + 1];
    const int bk = blockIdx.x;
    const int t = threadIdx.x;
    const int segBeg = bucketBase[bk];
    const int segEnd = bucketBase[bk + 1];
    const int segLen = segEnd - segBeg;
    const bool fits = (segLen <= CAP);

    if (t < BUCKET) {
        int ex = offG[bk * BUCKET + t];
        offL[t] = ex;
        cnt[t] = 0;
        int node = bk * BUCKET + t;
        if (node < N) rowStart[node] = segBeg + ex;
    }
    if (t == 0) offL[BUCKET] = segLen;
    if (bk == NB - 1 && t == 0) rowStart[N] = E;
    __syncthreads();

    // scatter: tmp -> LDS (+ global pairs, cached stores so L2 merges the block window)
    for (int e = segBeg + t; e < segEnd; e += 512) {
        unsigned long long rec = tmp[e];
        int dl = (int)(rec & (BUCKET - 1));
        int s  = (int)((rec >> NBITS) & 0xFFFFF);
        float w = __uint_as_float((unsigned int)(rec >> 32));
        float v = w * dis[s];                 // per-thread gather, 64 edges/instr
        int r = atomicAdd(&cnt[dl], 1);
        int pos = offL[dl] + r;
        int2 pr = make_int2(s, __float_as_int(v));
        pairs[segBeg + pos] = pr;
        if (fits) lp[pos] = pr;
    }
    __syncthreads();

    // aggregate: wave wv owns nodes wv*16 .. wv*16+15
    const int wv = t >> 6, lane = t & 63;
    for (int k = 0; k < 16; ++k) {
        const int nl = wv * 16 + k;
        const int node = bk * BUCKET + nl;
        if (node >= N) break;
        if (!((needed[node >> 5] >> (node & 31)) & 1u)) continue;
        const int beg = offL[nl], end = offL[nl + 1];
        float ax = 0.f, ay = 0.f;
        int j = beg;
        if (fits) {
            for (; j + 7 < end; j += 8) {
                int2 p[8];
                unsigned int h[8];
#pragma unroll
                for (int i = 0; i < 8; ++i) p[i] = lp[j + i];
#pragma unroll
                for (int i = 0; i < 8; ++i) h[i] = Hb[(size_t)p[i].x * 64 + lane];
#pragma unroll
                for (int i = 0; i < 8; ++i) {
                    float v = __int_as_float(p[i].y);
                    ax += bf16_lo(h[i]) * v;
                    ay += bf16_hi(h[i]) * v;
                }
            }
            for (; j < end; ++j) {
                int2 p0 = lp[j];
                unsigned int h0 = Hb[(size_t)p0.x * 64 + lane];
                float v0 = __int_as_float(p0.y);
                ax += bf16_lo(h0) * v0;
                ay += bf16_hi(h0) * v0;
            }
        } else {  // defensive fallback (never expected): read pairs from global
            const int2* gp = pairs + segBeg;
            for (; j + 7 < end; j += 8) {
                int2 p[8];
                unsigned int h[8];
#pragma unroll
                for (int i = 0; i < 8; ++i) p[i] = gp[j + i];
#pragma unroll
                for (int i = 0; i < 8; ++i) h[i] = Hb[(size_t)p[i].x * 64 + lane];
#pragma unroll
                for (int i = 0; i < 8; ++i) {
                    float v = __int_as_float(p[i].y);
                    ax += bf16_lo(h[i]) * v;
                    ay += bf16_hi(h[i]) * v;
                }
            }
            for (; j < end; ++j) {
                int2 p0 = gp[j];
                unsigned int h0 = Hb[(size_t)p0.x * 64 + lane];
                float v0 = __int_as_float(p0.y);
                ax += bf16_lo(h0) * v0;
                ay += bf16_hi(h0) * v0;
            }
        }
        float dd = dis[node];
        float sn = dd * dd;  // self-loop norm = 1/deg
        unsigned int hs = Hb[(size_t)node * 64 + lane];
        float2 bb = ((const float2*)b)[lane];
        float ox = fmaxf(ax * dd + bf16_lo(hs) * sn + bb.x, 0.f);
        float oy = fmaxf(ay * dd + bf16_hi(hs) * sn + bb.y, 0.f);
        __builtin_nontemporal_store(pack_bf16x2(ox, oy), outB + (size_t)node * 64 + lane);
    }
}

// ---------------- fused layer-2 at mask nodes: out = agg(B)@W2 + b2 ----------------
// (agg is linear, so agg(B@W2) = agg(B)@W2.) Wave per mask row: gather-aggregate B,
// park the row in LDS, then multiply by W2 staged in LDS (two 64-row halves). Also
// writes y labels. Replaces k_agg_mask_B + k_out_gemm (one launch, no aggB bounce).

__global__ __launch_bounds__(256) void k_mask_out(const unsigned int* __restrict__ Hb,
                                                  const int2* __restrict__ pairs,
                                                  const int* __restrict__ rowStart,
                                                  const float* __restrict__ dis,
                                                  const float* __restrict__ W2,
                                                  const float* __restrict__ b2,
                                                  const int* __restrict__ mask,
                                                  const int* __restrict__ y,
                                                  float* __restrict__ out) {
    __shared__ float w2s[64 * 132];   // 132 stride: float4-aligned stores, bank spread
    __shared__ float rowL[4][128];
    const int t = threadIdx.x;
    const int wv = t >> 6, lane = t & 63;
    const int i = blockIdx.x * 4 + wv;   // grid = M/4 exactly (1250*4 = 5000)
    const int node = mask[i];
    const int beg = rowStart[node], end = rowStart[node + 1];

    float ax = 0.f, ay = 0.f;
    int j = beg;
    for (; j + 7 < end; j += 8) {
        int2 p[8];
        unsigned int h[8];
#pragma unroll
        for (int ii = 0; ii < 8; ++ii) p[ii] = pairs[j + ii];
#pragma unroll
        for (int ii = 0; ii < 8; ++ii) h[ii] = Hb[(size_t)p[ii].x * 64 + lane];
#pragma unroll
        for (int ii = 0; ii < 8; ++ii) {
            float v = __int_as_float(p[ii].y);
            ax += bf16_lo(h[ii]) * v;
            ay += bf16_hi(h[ii]) * v;
        }
    }
    for (; j < end; ++j) {
        int2 p0 = pairs[j];
        unsigned int h0 = Hb[(size_t)p0.x * 64 + lane];
        float v0 = __int_as_float(p0.y);
        ax += bf16_lo(h0) * v0;
        ay += bf16_hi(h0) * v0;
    }
    {
        float dd = dis[node];
        float sn = dd * dd;
        unsigned int hs = Hb[(size_t)node * 64 + lane];
        rowL[wv][2 * lane]     = ax * dd + bf16_lo(hs) * sn;   // bias b2 added post-GEMM
        rowL[wv][2 * lane + 1] = ay * dd + bf16_hi(hs) * sn;
    }

    float2 bb = ((const float2*)b2)[lane];
    float acc0 = bb.x, acc1 = bb.y;
#pragma unroll
    for (int h0 = 0; h0 < 2; ++h0) {
        __syncthreads();
        for (int idx = t; idx < 2048; idx += 256) {   // stage 64 rows of W2 (float4 units)
            float4 v = ((const float4*)W2)[h0 * 2048 + idx];
            int k = (idx * 4) >> 7, n = (idx * 4) & 127;
            *(float4*)(&w2s[k * 132 + n]) = v;
        }
        __syncthreads();
#pragma unroll 8
        for (int k = 0; k < 64; ++k) {
            float a = rowL[wv][h0 * 64 + k];
            float2 w = *(const float2*)(&w2s[k * 132 + 2 * lane]);
            acc0 += a * w.x;
            acc1 += a * w.y;
        }
    }
    ((float2*)(out + (size_t)i * D))[lane] = make_float2(acc0, acc1);
    if (lane == 0) out[(size_t)M * D + i] = (float)y[node];
}

extern "C" void kernel_launch(void* const* d_in, const int* in_sizes, int n_in,
                              void* d_out, int out_size, void* d_ws, size_t ws_size,
                              hipStream_t stream) {
    const float* x  = (const float*)d_in[0];
    const float* ew = (const float*)d_in[1];
    const float* W1 = (const float*)d_in[2];
    const float* b1 = (const float*)d_in[3];
    const float* W2 = (const float*)d_in[4];
    const float* b2 = (const float*)d_in[5];
    const int* eidx = (const int*)d_in[6];
    const int* mask = (const int*)d_in[7];
    const int* y    = (const int*)d_in[8];
    const int* src = eidx;       // edge_index[0]
    const int* dst = eidx + E;   // edge_index[1]

    // Workspace layout (bytes):
    //   dis        @ 0       : N f32       (0.4 MB)
    //   rowStart   @ 512 KB  : N+1 i32     (0.4 MB)
    //   maskbit    @ 960 KB  : 16 KB bitmap }
    //   needed     @ 976 KB  : 16 KB bitmap }  zeroed together (40 KB memset)
    //   bucketCnt  @ 992 KB  : NB i32
    //   bucketBase @ 996 KB  : NB+1 i32
    //   gCursor    @ 1000 KB : NB i32
    //   Wt1        @ 1008 KB : 8192 u32   (32 KB)
    //   offG       @ 1040 KB : NB*128 i32 (400 KB)
    //   pairs      @ 2 MB    : E int2     (12.8 MB)
    //   tmp        @ 16 MB   : E u64      (12.8 MB)
    //   A  (bf16)  @ 29 MB   : N*D bf16   (25.6 MB)
    //   B  (bf16)  @ 55 MB   : N*D bf16   (25.6 MB)   total ~81 MB
    char* ws = (char*)d_ws;
    float* dis      = (float*)(ws);
    int*   rowStart = (int*)(ws + (size_t)512 * 1024);
    unsigned int* maskbit = (unsigned int*)(ws + (size_t)960 * 1024);
    unsigned int* needed  = (unsigned int*)(ws + (size_t)976 * 1024);
    int*   bucketCnt  = (int*)(ws + (size_t)992 * 1024);
    int*   bucketBase = (int*)(ws + (size_t)996 * 1024);
    int*   gCursor    = (int*)(ws + (size_t)1000 * 1024);
    unsigned int* Wt1 = (unsigned int*)(ws + (size_t)1008 * 1024);
    int*   offG     = (int*)(ws + (size_t)1040 * 1024);
    int2*  pairs    = (int2*)(ws + (size_t)2 * 1024 * 1024);
    unsigned long long* tmp = (unsigned long long*)(ws + (size_t)16 * 1024 * 1024);
    unsigned short* A  = (unsigned short*)(ws + (size_t)29 * 1024 * 1024);
    unsigned short* B  = (unsigned short*)(ws + (size_t)55 * 1024 * 1024);

    // --- zero bitmaps + bucket counters, then fused hist + W1 prep + maskbit ---
    (void)hipMemsetAsync(ws + (size_t)960 * 1024, 0, (size_t)40 * 1024, stream);
    hipLaunchKernelGGL(k_misc1, dim3(NPB + PREP_BLKS + MB_BLKS), dim3(256), 0, stream,
                       dst, bucketCnt, W1, Wt1, mask, maskbit, needed);

    // --- bucket scan (1 block) + needed-set edge scan ---
    hipLaunchKernelGGL(k_misc2, dim3(1 + NPB), dim3(256), 0, stream,
                       bucketCnt, bucketBase, gCursor, maskbit, src, dst, needed);

    // --- partition via atomic run reservation ---
    hipLaunchKernelGGL(k_part, dim3(NPP), dim3(1024), 0, stream,
                       src, dst, ew, gCursor, tmp);

    // --- local pass-A (dis, per-node offsets) fused with GEMM1 ---
    hipLaunchKernelGGL(k_local_g1, dim3(NB + MF_BLKS), dim3(256), 0, stream,
                       tmp, bucketBase, dis, offG, x, Wt1, A);

    // --- fused sort + layer-1 aggregate: B = relu(agg(A) + b1); also emits pairs/rowStart ---
    hipLaunchKernelGGL(k_sort_agg, dim3(NB), dim3(512), 0, stream,
                       tmp, bucketBase, offG, dis, needed, b1,
                       (const unsigned int*)A, rowStart, pairs, (unsigned int*)B);

    // --- fused layer-2 at mask nodes: out = agg(B)@W2 + b2 (+ labels) ---
    hipLaunchKernelGGL(k_mask_out, dim3(M / 4), dim3(256), 0, stream,
                       (const unsigned int*)B, pairs, rowStart, dis, W2, b2,
                       mask, y, (float*)d_out);
}

// Round 7
// 257.632 us; speedup vs baseline: 1.1737x; 1.0715x over previous
//
#include <hip/hip_runtime.h>

// Problem constants (fixed by the reference).
constexpr int N = 100000;   // nodes
constexpr int E = 1600000;  // edges
constexpr int D = 128;      // feature dim (both layers)
constexpr int M = 5000;     // mask size

constexpr int MF_BLKS = (N + 255) / 256;           // 391 mfma-gemm blocks (256 rows each)

// Counting-sort CSR build parameters.
// Bucket = dst>>7 (128 nodes) -> 782 buckets.
// k_part: atomic run-reservation (R3) + fused needed-set scan (R7).
// k_sort_agg: LDS-resident sort + aggregate, dynamic needed-node worklist (R7),
// pairs written to global only for masked dsts (mask pass reads ~5% of edges).
constexpr int NBITS = 7;
constexpr int BUCKET = 1 << NBITS;                 // 128 nodes per bucket
constexpr int NB  = (N + BUCKET - 1) / BUCKET;     // 782 buckets
constexpr int EB  = 2048;                          // edges per hist block
constexpr int NPB = (E + EB - 1) / EB;             // 782 hist blocks
constexpr int EBP = 8192;                          // edges per partition block
constexpr int NPP = (E + EBP - 1) / EBP;           // 196 partition blocks (1024 thr each)
constexpr int PREP_BLKS = 32;                      // weight-prep blocks (W1 only)
constexpr int MB_BLKS = (M + 255) / 256;           // 20 maskbit blocks
constexpr int CAP = 3072;                          // LDS pair capacity per bucket
                                                   // (bucket counts ~Poisson(2046), max ~2.3K)

typedef __attribute__((ext_vector_type(8))) short bf16x8;
typedef __attribute__((ext_vector_type(4))) float f32x4;

// ---------------- bf16 helpers (RNE pack, cheap unpack) ----------------

__device__ __forceinline__ unsigned int pack_bf16x2(float a, float b) {
    unsigned int ua = __float_as_uint(a);
    unsigned int ub = __float_as_uint(b);
    ua = (ua + 0x7FFFu + ((ua >> 16) & 1u)) >> 16;
    ub = (ub + 0x7FFFu + ((ub >> 16) & 1u)) & 0xFFFF0000u;
    return ua | ub;
}
__device__ __forceinline__ unsigned short bf16_rne(float a) {
    unsigned int ua = __float_as_uint(a);
    return (unsigned short)((ua + 0x7FFFu + ((ua >> 16) & 1u)) >> 16);
}
__device__ __forceinline__ float bf16_lo(unsigned int u) { return __uint_as_float(u << 16); }
__device__ __forceinline__ float bf16_hi(unsigned int u) { return __uint_as_float(u & 0xFFFF0000u); }

// ---------------- misc1: bucket hist (LDS + global atomics) + W1 prep + maskbit ----------------

__global__ __launch_bounds__(256) void k_misc1(const int* __restrict__ dst,
                                               int* __restrict__ bucketCnt,
                                               const float* __restrict__ W1,
                                               unsigned int* __restrict__ Wt1,
                                               const int* __restrict__ mask,
                                               unsigned int* __restrict__ maskbit,
                                               unsigned int* __restrict__ needed) {
    __shared__ int h[NB];
    const int t = threadIdx.x;
    if (blockIdx.x < NPB) {
        for (int i = t; i < NB; i += 256) h[i] = 0;
        __syncthreads();
        const int base = blockIdx.x * EB;
#pragma unroll
        for (int i = 0; i < 8; ++i) {
            int e = base + t + i * 256;
            if (e < E) {
                int b = __builtin_nontemporal_load(dst + e) >> NBITS;
                atomicAdd(&h[b], 1);
            }
        }
        __syncthreads();
        for (int i = t; i < NB; i += 256) {
            int c = h[i];
            if (c) atomicAdd(&bucketCnt[i], c);
        }
    } else if (blockIdx.x < NPB + PREP_BLKS) {
        int idx = (blockIdx.x - NPB) * 256 + t;   // 8192 total (W1 only; W2 used in fp32)
        int n = idx >> 6, kk = idx & 63;
        float a = W1[(2 * kk) * D + n];
        float b = W1[(2 * kk + 1) * D + n];
        Wt1[idx] = pack_bf16x2(a, b);
    } else {
        int i = (blockIdx.x - NPB - PREP_BLKS) * 256 + t;
        if (i < M) {
            int n = mask[i];
            atomicOr(&maskbit[n >> 5], 1u << (n & 31));
            atomicOr(&needed[n >> 5], 1u << (n & 31));  // masked nodes need their own row
        }
    }
}

// ---------------- scan: 1 block; exclusive scan bucketCnt -> bucketBase, gCursor ----------------

__global__ __launch_bounds__(256) void k_scan(const int* __restrict__ bucketCnt,
                                              int* __restrict__ bucketBase,
                                              int* __restrict__ gCursor) {
    __shared__ int waveS[4];
    const int t = threadIdx.x;
    const int lane = t & 63, wave = t >> 6;
    const int idx = t * 4;
    int c[4];
    int s = 0;
#pragma unroll
    for (int g = 0; g < 4; ++g) {
        c[g] = (idx + g < NB) ? bucketCnt[idx + g] : 0;
        s += c[g];
    }
    int v = s;
    for (int off = 1; off < 64; off <<= 1) {
        int u = __shfl_up(v, off);
        if (lane >= off) v += u;
    }
    if (lane == 63) waveS[wave] = v;
    __syncthreads();
    int wb = 0;
    for (int w = 0; w < 4; ++w) if (w < wave) wb += waveS[w];
    int run = wb + v - s;   // exclusive prefix
#pragma unroll
    for (int g = 0; g < 4; ++g) {
        int pos = idx + g;
        if (pos < NB) {
            bucketBase[pos] = run;
            gCursor[pos] = run;
        }
        run += c[g];
    }
    if (t == 255) bucketBase[NB] = E;
}

// ---------------- partition + needed-scan: register-stash + atomic run reservation ----------------
// record: bits[6:0]=d&127, bits[26:7]=src, bits[63:32]=ew bits.
// Fused needed-set scan (src/dst already in registers; maskbit is L1-resident 12.5KB).

__global__ __launch_bounds__(1024) void k_part(const int* __restrict__ src,
                                               const int* __restrict__ dst,
                                               const float* __restrict__ ew,
                                               int* __restrict__ gCursor,
                                               unsigned long long* __restrict__ tmp,
                                               const unsigned int* __restrict__ maskbit,
                                               unsigned int* __restrict__ needed) {
    __shared__ int cnt[NB];
    __shared__ int off[NB];
    __shared__ int rk[NB];
    const int t = threadIdx.x;
    for (int i = t; i < NB; i += 1024) { cnt[i] = 0; rk[i] = 0; }
    __syncthreads();

    const int eb = blockIdx.x * EBP;
    int d_[8], s_[8];
    float w_[8];
#pragma unroll
    for (int i = 0; i < 8; ++i) {
        int e = eb + t + i * 1024;
        if (e < E) {
            d_[i] = __builtin_nontemporal_load(dst + e);
            s_[i] = __builtin_nontemporal_load(src + e);
            w_[i] = __builtin_nontemporal_load(ew + e);
            atomicAdd(&cnt[d_[i] >> NBITS], 1);
        } else {
            d_[i] = -1;
        }
    }
    __syncthreads();

    for (int i = t; i < NB; i += 1024) {
        int c = cnt[i];
        if (c > 0) off[i] = atomicAdd(&gCursor[i], c);
    }
    __syncthreads();

#pragma unroll
    for (int i = 0; i < 8; ++i) {
        if (d_[i] >= 0) {
            int b = d_[i] >> NBITS;
            int r = atomicAdd(&rk[b], 1);
            unsigned long long rec =
                ((unsigned long long)(unsigned int)__float_as_int(w_[i]) << 32) |
                ((unsigned int)s_[i] << NBITS) | (unsigned int)(d_[i] & (BUCKET - 1));
            tmp[(size_t)off[b] + r] = rec;   // cached store: L2 merges the ~84B runs
            if ((maskbit[d_[i] >> 5] >> (d_[i] & 31)) & 1u)
                atomicOr(&needed[s_[i] >> 5], 1u << (s_[i] & 31));
        }
    }
}

// ---------------- shared-memory union: GEMM W-tile OR local-sort arrays ----------------

union SMem {
    unsigned int Ws[128 * 68];
    struct { int cnt[BUCKET]; float wsum[BUCKET]; int waveS[2]; } l;
};

// ---------------- MFMA GEMM body: 256 rows/block, 4 waves; wave = 64 rows x 128 cols ----------------
// A-frag: A[m=lane&15][k=quad*8+j]; B-frag: B[k=quad*8+j][n=lane&15];
// D: col=lane&15, row=quad*4+reg  (HW-verified layouts, 16x16x32 bf16).
// W^T staged in LDS with 68-uint row stride (bank-conflict padding).

template <bool BF16IN>
__device__ __forceinline__ void gemm_mfma_body(unsigned int* __restrict__ Ws,
                                               const void* __restrict__ Xin,
                                               const unsigned int* __restrict__ Wt,
                                               unsigned short* __restrict__ out, int blk) {
    const int t = threadIdx.x;
#pragma unroll
    for (int i = 0; i < 8; ++i) {
        int f4 = t + i * 256;        // uint4 index, 2048 total
        int n = f4 >> 4;
        int k4 = f4 & 15;
        uint4 w = ((const uint4*)Wt)[f4];
        *(uint4*)(&Ws[n * 68 + k4 * 4]) = w;
    }
    __syncthreads();

    const int wv = t >> 6, lane = t & 63;
    const int q = lane >> 4, l15 = lane & 15;
    const int rowBase = blk * 256 + wv * 64;

    f32x4 acc[4][8] = {};
#pragma unroll
    for (int kc = 0; kc < 4; ++kc) {
        bf16x8 af[4];
#pragma unroll
        for (int rt = 0; rt < 4; ++rt) {
            int row = rowBase + rt * 16 + l15;
            if (row > N - 1) row = N - 1;   // tail: duplicate last row, stores guarded
            union { uint4 u; bf16x8 v; } cv;
            if (BF16IN) {
                cv.u = *(const uint4*)((const unsigned int*)Xin + (size_t)row * 64 + kc * 16 + q * 4);
            } else {
                const float* xr = (const float*)Xin + (size_t)row * D + kc * 32 + q * 8;
                float4 x0 = *(const float4*)xr;
                float4 x1 = *(const float4*)(xr + 4);
                cv.u.x = pack_bf16x2(x0.x, x0.y);
                cv.u.y = pack_bf16x2(x0.z, x0.w);
                cv.u.z = pack_bf16x2(x1.x, x1.y);
                cv.u.w = pack_bf16x2(x1.z, x1.w);
            }
            af[rt] = cv.v;
        }
#pragma unroll
        for (int ct = 0; ct < 8; ++ct) {
            union { uint4 u; bf16x8 v; } bv;
            bv.u = *(const uint4*)(&Ws[(ct * 16 + l15) * 68 + kc * 16 + q * 4]);
#pragma unroll
            for (int rt = 0; rt < 4; ++rt)
                acc[rt][ct] = __builtin_amdgcn_mfma_f32_16x16x32_bf16(af[rt], bv.v, acc[rt][ct], 0, 0, 0);
        }
    }

#pragma unroll
    for (int rt = 0; rt < 4; ++rt) {
#pragma unroll
        for (int ct = 0; ct < 8; ++ct) {
            int col = ct * 16 + l15;
#pragma unroll
            for (int r = 0; r < 4; ++r) {
                int row = rowBase + rt * 16 + q * 4 + r;
                if (row < N) out[(size_t)row * D + col] = bf16_rne(acc[rt][ct][r]);
            }
        }
    }
}

// ---- local pass-A: per-bucket counts -> dis + exclusive per-node offsets (offG). ----

__device__ __forceinline__ void local_a_body(SMem& sm,
                                             const unsigned long long* __restrict__ tmp,
                                             const int* __restrict__ bucketBase,
                                             float* __restrict__ dis,
                                             int* __restrict__ offG) {
    const int b = blockIdx.x;
    const int t = threadIdx.x;
    const int segBeg = bucketBase[b];
    const int segEnd = bucketBase[b + 1];

    int*   cnt   = sm.l.cnt;
    float* wsum  = sm.l.wsum;
    int*   waveS = sm.l.waveS;
    if (t < BUCKET) { cnt[t] = 0; wsum[t] = 0.f; }
    __syncthreads();

    for (int e = segBeg + t; e < segEnd; e += 256) {
        unsigned long long rec = tmp[e];
        int dl = (int)(rec & (BUCKET - 1));
        float w = __uint_as_float((unsigned int)(rec >> 32));
        atomicAdd(&cnt[dl], 1);
        atomicAdd(&wsum[dl], w);
    }
    __syncthreads();

    const int lane = t & 63, wv = t >> 6;
    const int pv = (t < BUCKET) ? cnt[t] : 0;
    int v = pv;
    for (int o = 1; o < 64; o <<= 1) {
        int u = __shfl_up(v, o);
        if (lane >= o) v += u;
    }
    if (lane == 63 && wv < 2) waveS[wv] = v;
    __syncthreads();
    if (t < BUCKET) {
        const int wb = (wv == 1) ? waveS[0] : 0;
        const int ex = wb + v - pv;
        offG[b * BUCKET + t] = ex;
        const int node = b * BUCKET + t;
        if (node < N) dis[node] = rsqrtf(1.0f + wsum[t]);
    }
}

// ---------------- fused: local pass-A (blocks 0..NB) + GEMM1 A=x@W1 (blocks NB..) ----

__global__ __launch_bounds__(256) void k_local_g1(const unsigned long long* __restrict__ tmp,
                                                  const int* __restrict__ bucketBase,
                                                  float* __restrict__ dis,
                                                  int* __restrict__ offG,
                                                  const float* __restrict__ x,
                                                  const unsigned int* __restrict__ Wt1,
                                                  unsigned short* __restrict__ A) {
    __shared__ SMem sm;
    if (blockIdx.x < NB) {
        local_a_body(sm, tmp, bucketBase, dis, offG);
    } else {
        gemm_mfma_body<false>(sm.Ws, x, Wt1, A, blockIdx.x - NB);
    }
}

// ---------------- fused sort+aggregate: block (512 thr) per bucket ----------------
// Phase 1: stream tmp segment once; scatter (src, ew*dis[src]) pairs into LDS at the
// node-sorted position; global pairs written ONLY for masked dsts (mask pass reads
// just those ranges). Phase 2: waves pop needed nodes from an LDS worklist (dynamic
// balance -- R6's fixed 16-node slices left waves idle at 43% occupancy).

__global__ __launch_bounds__(512) void k_sort_agg(const unsigned long long* __restrict__ tmp,
                                                  const int* __restrict__ bucketBase,
                                                  const int* __restrict__ offG,
                                                  const float* __restrict__ dis,
                                                  const unsigned int* __restrict__ needed,
                                                  const unsigned int* __restrict__ maskbit,
                                                  const float* __restrict__ b,
                                                  const unsigned int* __restrict__ Hb,
                                                  int* __restrict__ rowStart,
                                                  int2* __restrict__ pairs,
                                                  unsigned int* __restrict__ outB) {
    __shared__ int2 lp[CAP];
    __shared__ int cnt[BUCKET];
    __shared__ int offL[BUCKET + 1];
    __shared__ int wl[BUCKET];
    __shared__ int nw, wcur;
    const int bk = blockIdx.x;
    const int t = threadIdx.x;
    const int segBeg = bucketBase[bk];
    const int segEnd = bucketBase[bk + 1];
    const int segLen = segEnd - segBeg;
    const bool fits = (segLen <= CAP);

    if (t == 0) { nw = 0; wcur = 0; offL[BUCKET] = segLen; }
    __syncthreads();
    if (t < BUCKET) {
        int ex = offG[bk * BUCKET + t];
        offL[t] = ex;
        cnt[t] = 0;
        int node = bk * BUCKET + t;
        if (node < N) {
            rowStart[node] = segBeg + ex;
            if ((needed[node >> 5] >> (node & 31)) & 1u) {
                int r = atomicAdd(&nw, 1);
                wl[r] = t;
            }
        }
    }
    if (bk == NB - 1 && t == 0) rowStart[N] = E;
    // this bucket's 128 maskbit bits, kept in registers
    const uint4 mb4 = ((const uint4*)maskbit)[bk];
    __syncthreads();

    // scatter: tmp -> LDS; global pairs only where dst is masked (or overflow fallback)
    for (int e = segBeg + t; e < segEnd; e += 512) {
        unsigned long long rec = tmp[e];
        int dl = (int)(rec & (BUCKET - 1));
        int s  = (int)((rec >> NBITS) & 0xFFFFF);
        float w = __uint_as_float((unsigned int)(rec >> 32));
        float v = w * dis[s];                 // per-thread gather, 64 edges/instr
        int r = atomicAdd(&cnt[dl], 1);
        int pos = offL[dl] + r;
        int2 pr = make_int2(s, __float_as_int(v));
        unsigned int mw = (dl < 32) ? mb4.x : (dl < 64) ? mb4.y : (dl < 96) ? mb4.z : mb4.w;
        if (((mw >> (dl & 31)) & 1u) || !fits) pairs[segBeg + pos] = pr;
        if (fits) lp[pos] = pr;
    }
    __syncthreads();

    // aggregate: waves pop needed nodes from the worklist
    const int lane = t & 63;
    for (;;) {
        int idx;
        if (lane == 0) idx = atomicAdd(&wcur, 1);
        idx = __shfl(idx, 0);
        if (idx >= nw) break;
        const int nl = wl[idx];
        const int node = bk * BUCKET + nl;
        const int beg = offL[nl], end = offL[nl + 1];
        float ax = 0.f, ay = 0.f;
        int j = beg;
        if (fits) {
            for (; j + 7 < end; j += 8) {
                int2 p[8];
                unsigned int h[8];
#pragma unroll
                for (int i = 0; i < 8; ++i) p[i] = lp[j + i];
#pragma unroll
                for (int i = 0; i < 8; ++i) h[i] = Hb[(size_t)p[i].x * 64 + lane];
#pragma unroll
                for (int i = 0; i < 8; ++i) {
                    float v = __int_as_float(p[i].y);
                    ax += bf16_lo(h[i]) * v;
                    ay += bf16_hi(h[i]) * v;
                }
            }
            for (; j < end; ++j) {
                int2 p0 = lp[j];
                unsigned int h0 = Hb[(size_t)p0.x * 64 + lane];
                float v0 = __int_as_float(p0.y);
                ax += bf16_lo(h0) * v0;
                ay += bf16_hi(h0) * v0;
            }
        } else {  // defensive fallback (never expected): read pairs from global
            const int2* gp = pairs + segBeg;
            for (; j + 7 < end; j += 8) {
                int2 p[8];
                unsigned int h[8];
#pragma unroll
                for (int i = 0; i < 8; ++i) p[i] = gp[j + i];
#pragma unroll
                for (int i = 0; i < 8; ++i) h[i] = Hb[(size_t)p[i].x * 64 + lane];
#pragma unroll
                for (int i = 0; i < 8; ++i) {
                    float v = __int_as_float(p[i].y);
                    ax += bf16_lo(h[i]) * v;
                    ay += bf16_hi(h[i]) * v;
                }
            }
            for (; j < end; ++j) {
                int2 p0 = gp[j];
                unsigned int h0 = Hb[(size_t)p0.x * 64 + lane];
                float v0 = __int_as_float(p0.y);
                ax += bf16_lo(h0) * v0;
                ay += bf16_hi(h0) * v0;
            }
        }
        float dd = dis[node];
        float sn = dd * dd;  // self-loop norm = 1/deg
        unsigned int hs = Hb[(size_t)node * 64 + lane];
        float2 bb = ((const float2*)b)[lane];
        float ox = fmaxf(ax * dd + bf16_lo(hs) * sn + bb.x, 0.f);
        float oy = fmaxf(ay * dd + bf16_hi(hs) * sn + bb.y, 0.f);
        __builtin_nontemporal_store(pack_bf16x2(ox, oy), outB + (size_t)node * 64 + lane);
    }
}

// ---------------- fused layer-2 at mask nodes: out = agg(B)@W2 + b2 ----------------
// (agg is linear, so agg(B@W2) = agg(B)@W2.) Wave per mask row: gather-aggregate B,
// park the row in LDS, then multiply by W2 staged in LDS (two 64-row halves).

__global__ __launch_bounds__(256) void k_mask_out(const unsigned int* __restrict__ Hb,
                                                  const int2* __restrict__ pairs,
                                                  const int* __restrict__ rowStart,
                                                  const float* __restrict__ dis,
                                                  const float* __restrict__ W2,
                                                  const float* __restrict__ b2,
                                                  const int* __restrict__ mask,
                                                  const int* __restrict__ y,
                                                  float* __restrict__ out) {
    __shared__ float w2s[64 * 132];   // 132 stride: float4-aligned stores, bank spread
    __shared__ float rowL[4][128];
    const int t = threadIdx.x;
    const int wv = t >> 6, lane = t & 63;
    const int i = blockIdx.x * 4 + wv;   // grid = M/4 exactly (1250*4 = 5000)
    const int node = mask[i];
    const int beg = rowStart[node], end = rowStart[node + 1];

    float ax = 0.f, ay = 0.f;
    int j = beg;
    for (; j + 7 < end; j += 8) {
        int2 p[8];
        unsigned int h[8];
#pragma unroll
        for (int ii = 0; ii < 8; ++ii) p[ii] = pairs[j + ii];
#pragma unroll
        for (int ii = 0; ii < 8; ++ii) h[ii] = Hb[(size_t)p[ii].x * 64 + lane];
#pragma unroll
        for (int ii = 0; ii < 8; ++ii) {
            float v = __int_as_float(p[ii].y);
            ax += bf16_lo(h[ii]) * v;
            ay += bf16_hi(h[ii]) * v;
        }
    }
    for (; j < end; ++j) {
        int2 p0 = pairs[j];
        unsigned int h0 = Hb[(size_t)p0.x * 64 + lane];
        float v0 = __int_as_float(p0.y);
        ax += bf16_lo(h0) * v0;
        ay += bf16_hi(h0) * v0;
    }
    {
        float dd = dis[node];
        float sn = dd * dd;
        unsigned int hs = Hb[(size_t)node * 64 + lane];
        rowL[wv][2 * lane]     = ax * dd + bf16_lo(hs) * sn;   // bias b2 added post-GEMM
        rowL[wv][2 * lane + 1] = ay * dd + bf16_hi(hs) * sn;
    }

    float2 bb = ((const float2*)b2)[lane];
    float acc0 = bb.x, acc1 = bb.y;
#pragma unroll
    for (int h0 = 0; h0 < 2; ++h0) {
        __syncthreads();
        for (int idx = t; idx < 2048; idx += 256) {   // stage 64 rows of W2 (float4 units)
            float4 v = ((const float4*)W2)[h0 * 2048 + idx];
            int k = (idx * 4) >> 7, n = (idx * 4) & 127;
            *(float4*)(&w2s[k * 132 + n]) = v;
        }
        __syncthreads();
#pragma unroll 8
        for (int k = 0; k < 64; ++k) {
            float a = rowL[wv][h0 * 64 + k];
            float2 w = *(const float2*)(&w2s[k * 132 + 2 * lane]);
            acc0 += a * w.x;
            acc1 += a * w.y;
        }
    }
    ((float2*)(out + (size_t)i * D))[lane] = make_float2(acc0, acc1);
    if (lane == 0) out[(size_t)M * D + i] = (float)y[node];
}

extern "C" void kernel_launch(void* const* d_in, const int* in_sizes, int n_in,
                              void* d_out, int out_size, void* d_ws, size_t ws_size,
                              hipStream_t stream) {
    const float* x  = (const float*)d_in[0];
    const float* ew = (const float*)d_in[1];
    const float* W1 = (const float*)d_in[2];
    const float* b1 = (const float*)d_in[3];
    const float* W2 = (const float*)d_in[4];
    const float* b2 = (const float*)d_in[5];
    const int* eidx = (const int*)d_in[6];
    const int* mask = (const int*)d_in[7];
    const int* y    = (const int*)d_in[8];
    const int* src = eidx;       // edge_index[0]
    const int* dst = eidx + E;   // edge_index[1]

    // Workspace layout (bytes):
    //   dis        @ 0       : N f32       (0.4 MB)
    //   rowStart   @ 512 KB  : N+1 i32     (0.4 MB)
    //   maskbit    @ 960 KB  : 16 KB bitmap }
    //   needed     @ 976 KB  : 16 KB bitmap }  zeroed together (40 KB memset)
    //   bucketCnt  @ 992 KB  : NB i32
    //   bucketBase @ 996 KB  : NB+1 i32
    //   gCursor    @ 1000 KB : NB i32
    //   Wt1        @ 1008 KB : 8192 u32   (32 KB)
    //   offG       @ 1040 KB : NB*128 i32 (400 KB)
    //   pairs      @ 2 MB    : E int2     (12.8 MB, sparsely written)
    //   tmp        @ 16 MB   : E u64      (12.8 MB)
    //   A  (bf16)  @ 29 MB   : N*D bf16   (25.6 MB)
    //   B  (bf16)  @ 55 MB   : N*D bf16   (25.6 MB)   total ~81 MB
    char* ws = (char*)d_ws;
    float* dis      = (float*)(ws);
    int*   rowStart = (int*)(ws + (size_t)512 * 1024);
    unsigned int* maskbit = (unsigned int*)(ws + (size_t)960 * 1024);
    unsigned int* needed  = (unsigned int*)(ws + (size_t)976 * 1024);
    int*   bucketCnt  = (int*)(ws + (size_t)992 * 1024);
    int*   bucketBase = (int*)(ws + (size_t)996 * 1024);
    int*   gCursor    = (int*)(ws + (size_t)1000 * 1024);
    unsigned int* Wt1 = (unsigned int*)(ws + (size_t)1008 * 1024);
    int*   offG     = (int*)(ws + (size_t)1040 * 1024);
    int2*  pairs    = (int2*)(ws + (size_t)2 * 1024 * 1024);
    unsigned long long* tmp = (unsigned long long*)(ws + (size_t)16 * 1024 * 1024);
    unsigned short* A  = (unsigned short*)(ws + (size_t)29 * 1024 * 1024);
    unsigned short* B  = (unsigned short*)(ws + (size_t)55 * 1024 * 1024);

    // --- zero bitmaps + bucket counters, then fused hist + W1 prep + maskbit ---
    (void)hipMemsetAsync(ws + (size_t)960 * 1024, 0, (size_t)40 * 1024, stream);
    hipLaunchKernelGGL(k_misc1, dim3(NPB + PREP_BLKS + MB_BLKS), dim3(256), 0, stream,
                       dst, bucketCnt, W1, Wt1, mask, maskbit, needed);

    // --- bucket scan (1 block) ---
    hipLaunchKernelGGL(k_scan, dim3(1), dim3(256), 0, stream,
                       bucketCnt, bucketBase, gCursor);

    // --- partition via atomic run reservation + fused needed-set scan ---
    hipLaunchKernelGGL(k_part, dim3(NPP), dim3(1024), 0, stream,
                       src, dst, ew, gCursor, tmp, maskbit, needed);

    // --- local pass-A (dis, per-node offsets) fused with GEMM1 ---
    hipLaunchKernelGGL(k_local_g1, dim3(NB + MF_BLKS), dim3(256), 0, stream,
                       tmp, bucketBase, dis, offG, x, Wt1, A);

    // --- fused sort + layer-1 aggregate: B = relu(agg(A) + b1); pairs for masked dsts ---
    hipLaunchKernelGGL(k_sort_agg, dim3(NB), dim3(512), 0, stream,
                       tmp, bucketBase, offG, dis, needed, maskbit, b1,
                       (const unsigned int*)A, rowStart, pairs, (unsigned int*)B);

    // --- fused layer-2 at mask nodes: out = agg(B)@W2 + b2 (+ labels) ---
    hipLaunchKernelGGL(k_mask_out, dim3(M / 4), dim3(256), 0, stream,
                       (const unsigned int*)B, pairs, rowStart, dis, W2, b2,
                       mask, y, (float*)d_out);
}